// Round 1
// baseline (382.575 us; speedup 1.0000x reference)
//
#include <hip/hip_runtime.h>

typedef unsigned short u16;
typedef __attribute__((ext_vector_type(8))) short bf16x8;   // 8 x bf16 (4 VGPRs)
typedef __attribute__((ext_vector_type(4))) short s16x4;
typedef __attribute__((ext_vector_type(4))) float f32x4;

#define DEV __device__ __forceinline__

DEV u16 f2bf(float f) {                       // fp32 -> bf16 bits, RNE
  union { float f; unsigned u; } v; v.f = f;
  unsigned r = v.u + 0x7fffu + ((v.u >> 16) & 1u);
  return (u16)(r >> 16);
}

// ---- weight cast + transpose: w[K][N] f32 -> wt[N][K] bf16 ----------------
__global__ __launch_bounds__(256) void wcastT(const float* __restrict__ w,
                                              u16* __restrict__ wt, int K, int N) {
  __shared__ float t[32][33];
  int n0 = blockIdx.x * 32, k0 = blockIdx.y * 32;
  int tx = threadIdx.x & 31, ty = threadIdx.x >> 5;
#pragma unroll
  for (int i = 0; i < 32; i += 8)
    t[ty + i][tx] = w[(size_t)(k0 + ty + i) * N + n0 + tx];
  __syncthreads();
#pragma unroll
  for (int i = 0; i < 32; i += 8)
    wt[(size_t)(n0 + ty + i) * K + k0 + tx] = f2bf(t[tx][ty + i]);
}

// ---- V transpose per (b,h): v[s][h*64+d] -> vt[(b*16+h)*64+d][s] ----------
__global__ __launch_bounds__(256) void vtransp(const u16* __restrict__ v,
                                               u16* __restrict__ vt) {
  __shared__ u16 t[32][34];
  int s0 = blockIdx.x * 32, d0 = blockIdx.y * 32;
  int bh = blockIdx.z; int b = bh >> 4, h = bh & 15;
  int tx = threadIdx.x & 31, ty = threadIdx.x >> 5;
#pragma unroll
  for (int i = 0; i < 32; i += 8)
    t[ty + i][tx] = v[(size_t)(b * 2048 + s0 + ty + i) * 1024 + h * 64 + d0 + tx];
  __syncthreads();
#pragma unroll
  for (int i = 0; i < 32; i += 8)
    vt[((size_t)(b * 16 + h) * 64 + d0 + ty + i) * 2048 + s0 + tx] = t[tx][ty + i];
}

// ---- LayerNorm (1024 cols, no affine) f32 -> bf16 -------------------------
__global__ __launch_bounds__(256) void ln_kernel(const float* __restrict__ x,
                                                 u16* __restrict__ out) {
  int row = blockIdx.x, tid = threadIdx.x;
  const float4* xr = (const float4*)(x + (size_t)row * 1024);
  float4 f = xr[tid];
  float s = f.x + f.y + f.z + f.w;
  float s2 = f.x * f.x + f.y * f.y + f.z * f.z + f.w * f.w;
#pragma unroll
  for (int o = 1; o < 64; o <<= 1) { s += __shfl_xor(s, o); s2 += __shfl_xor(s2, o); }
  __shared__ float red[2][4];
  int wid = tid >> 6;
  if ((tid & 63) == 0) { red[0][wid] = s; red[1][wid] = s2; }
  __syncthreads();
  float tot  = red[0][0] + red[0][1] + red[0][2] + red[0][3];
  float tot2 = red[1][0] + red[1][1] + red[1][2] + red[1][3];
  float mu = tot * (1.0f / 1024.0f);
  float var = tot2 * (1.0f / 1024.0f) - mu * mu;
  float rstd = rsqrtf(var + 1e-5f);
  s16x4 o4;
  o4[0] = (short)f2bf((f.x - mu) * rstd);
  o4[1] = (short)f2bf((f.y - mu) * rstd);
  o4[2] = (short)f2bf((f.z - mu) * rstd);
  o4[3] = (short)f2bf((f.w - mu) * rstd);
  *(s16x4*)(out + (size_t)row * 1024 + tid * 4) = o4;
}

// ---- GEMM: C[M,N] = A[M,K](bf16) * Bt[N,K]^T(bf16), fused epilogues -------
// 128x128 tile, BK=32, 4 waves x (64x64), m97-verified fragment mapping.
// MODE 0: qkv split -> o0/o1/o2 bf16    MODE 1: outF = resid + C (f32)
// MODE 2: o0 = gelu(C + bias) bf16      MODE 3: outF = resid + bias + C (f32)
template <int MODE>
__global__ __launch_bounds__(256) void gemm_bt(
    const u16* __restrict__ A, const u16* __restrict__ Bt, int N, int K,
    const float* __restrict__ resid, const float* __restrict__ bias,
    float* __restrict__ outF, u16* __restrict__ o0, u16* __restrict__ o1,
    u16* __restrict__ o2) {
  constexpr int LDT = 40;                       // 32 + 8 pad (2-way conflicts only)
  __shared__ __align__(16) u16 lA[128 * LDT];
  __shared__ __align__(16) u16 lB[128 * LDT];
  int tid = threadIdx.x;
  int lane = tid & 63, wid = tid >> 6;
  int lr = lane & 15, lg = lane >> 4;
  int rowBase = blockIdx.y * 128, colBase = blockIdx.x * 128;
  int wr = (wid >> 1) * 64, wc = (wid & 1) * 64;
  int sr = tid >> 2, sc = (tid & 3) * 8;        // staging: 64 rows x 32 cols per pass

  f32x4 acc[4][4];
  f32x4 zero = {0.f, 0.f, 0.f, 0.f};
#pragma unroll
  for (int m = 0; m < 4; m++)
#pragma unroll
    for (int n = 0; n < 4; n++) acc[m][n] = zero;

  const u16* ga = A + (size_t)(rowBase + sr) * K + sc;
  const u16* gb = Bt + (size_t)(colBase + sr) * K + sc;

  for (int k0 = 0; k0 < K; k0 += 32) {
    bf16x8 va0 = *(const bf16x8*)(ga + k0);
    bf16x8 va1 = *(const bf16x8*)(ga + k0 + (size_t)64 * K);
    bf16x8 vb0 = *(const bf16x8*)(gb + k0);
    bf16x8 vb1 = *(const bf16x8*)(gb + k0 + (size_t)64 * K);
    __syncthreads();                            // prior iter's frag reads done
    *(bf16x8*)&lA[sr * LDT + sc] = va0;
    *(bf16x8*)&lA[(sr + 64) * LDT + sc] = va1;
    *(bf16x8*)&lB[sr * LDT + sc] = vb0;
    *(bf16x8*)&lB[(sr + 64) * LDT + sc] = vb1;
    __syncthreads();
    bf16x8 af[4], bfv[4];
#pragma unroll
    for (int m = 0; m < 4; m++)
      af[m] = *(const bf16x8*)&lA[(wr + m * 16 + lr) * LDT + lg * 8];
#pragma unroll
    for (int n = 0; n < 4; n++)
      bfv[n] = *(const bf16x8*)&lB[(wc + n * 16 + lr) * LDT + lg * 8];
#pragma unroll
    for (int m = 0; m < 4; m++)
#pragma unroll
      for (int n = 0; n < 4; n++)
        acc[m][n] = __builtin_amdgcn_mfma_f32_16x16x32_bf16(af[m], bfv[n], acc[m][n], 0, 0, 0);
  }

#pragma unroll
  for (int m = 0; m < 4; m++) {
    int grow0 = rowBase + wr + m * 16 + lg * 4;
#pragma unroll
    for (int n = 0; n < 4; n++) {
      int gcol = colBase + wc + n * 16 + lr;
#pragma unroll
      for (int j = 0; j < 4; j++) {
        int grow = grow0 + j;
        float val = acc[m][n][j];
        if constexpr (MODE == 0) {
          u16* dst = (gcol < 1024) ? o0 : ((gcol < 2048) ? o1 : o2);
          dst[(size_t)grow * 1024 + (gcol & 1023)] = f2bf(val);
        } else if constexpr (MODE == 1) {
          size_t idx = (size_t)grow * N + gcol;
          outF[idx] = resid[idx] + val;
        } else if constexpr (MODE == 2) {
          float g = val + bias[gcol];
          float c3 = 0.7978845608028654f * (g + 0.044715f * g * g * g);
          o0[(size_t)grow * N + gcol] = f2bf(0.5f * g * (1.0f + tanhf(c3)));
        } else {
          size_t idx = (size_t)grow * N + gcol;
          outF[idx] = resid[idx] + bias[gcol] + val;
        }
      }
    }
  }
}

// ---- Flash attention: block = (b, h, 128 q-rows); 4 waves x 32 rows -------
__global__ __launch_bounds__(256) void attn_kernel(const u16* __restrict__ q,
                                                   const u16* __restrict__ k,
                                                   const u16* __restrict__ vt,
                                                   u16* __restrict__ o) {
  __shared__ __align__(16) u16 lK[64 * 72];     // [kv][d] pad->72
  __shared__ __align__(16) u16 lV[64 * 72];     // [d][kv] pad->72
  __shared__ __align__(16) u16 lP[4][32 * 72];  // per-wave P re-layout
  const int S = 2048, E = 1024;
  int qt = blockIdx.x, h = blockIdx.y, b = blockIdx.z;
  int tid = threadIdx.x, wid = tid >> 6, lane = tid & 63;
  int lr = lane & 15, lg = lane >> 4;

  const u16* qp = q + ((size_t)b * S + qt * 128 + wid * 32) * E + h * 64;
  const u16* kp = k + (size_t)b * S * E + h * 64;
  const u16* vp = vt + ((size_t)(b * 16 + h) * 64) * S;

  bf16x8 aQ[2][2];                              // Q hoisted to registers
#pragma unroll
  for (int m = 0; m < 2; m++)
#pragma unroll
    for (int kk = 0; kk < 2; kk++)
      aQ[m][kk] = *(const bf16x8*)(qp + (size_t)(m * 16 + lr) * E + kk * 32 + lg * 8);

  f32x4 accO[2][4];
  float Mx[2][4], Ls[2][4];
  f32x4 zero = {0.f, 0.f, 0.f, 0.f};
#pragma unroll
  for (int m = 0; m < 2; m++)
#pragma unroll
    for (int j = 0; j < 4; j++) { Mx[m][j] = -1e30f; Ls[m][j] = 0.f; }
#pragma unroll
  for (int m = 0; m < 2; m++)
#pragma unroll
    for (int nn = 0; nn < 4; nn++) accO[m][nn] = zero;

  int sr_ = tid >> 3, sc_ = (tid & 7) * 8;      // staging: 32 rows x 64 cols / pass

  for (int kv0 = 0; kv0 < S; kv0 += 64) {
    bf16x8 k0v = *(const bf16x8*)(kp + (size_t)(kv0 + sr_) * E + sc_);
    bf16x8 k1v = *(const bf16x8*)(kp + (size_t)(kv0 + 32 + sr_) * E + sc_);
    bf16x8 v0v = *(const bf16x8*)(vp + (size_t)sr_ * S + kv0 + sc_);
    bf16x8 v1v = *(const bf16x8*)(vp + (size_t)(32 + sr_) * S + kv0 + sc_);
    __syncthreads();                            // prior tile fully consumed
    *(bf16x8*)&lK[sr_ * 72 + sc_] = k0v;
    *(bf16x8*)&lK[(32 + sr_) * 72 + sc_] = k1v;
    *(bf16x8*)&lV[sr_ * 72 + sc_] = v0v;
    *(bf16x8*)&lV[(32 + sr_) * 72 + sc_] = v1v;
    __syncthreads();

    // QK^T: S[q 32][kv 64]
    f32x4 sc4[2][4];
#pragma unroll
    for (int m = 0; m < 2; m++)
#pragma unroll
      for (int n = 0; n < 4; n++) sc4[m][n] = zero;
#pragma unroll
    for (int n = 0; n < 4; n++) {
      bf16x8 bk0 = *(const bf16x8*)&lK[(n * 16 + lr) * 72 + lg * 8];
      bf16x8 bk1 = *(const bf16x8*)&lK[(n * 16 + lr) * 72 + 32 + lg * 8];
#pragma unroll
      for (int m = 0; m < 2; m++) {
        sc4[m][n] = __builtin_amdgcn_mfma_f32_16x16x32_bf16(aQ[m][0], bk0, sc4[m][n], 0, 0, 0);
        sc4[m][n] = __builtin_amdgcn_mfma_f32_16x16x32_bf16(aQ[m][1], bk1, sc4[m][n], 0, 0, 0);
      }
    }

    // online softmax per q-row (wave-parallel over the 16-lane col groups)
#pragma unroll
    for (int m = 0; m < 2; m++)
#pragma unroll
      for (int j = 0; j < 4; j++) {
        float sv[4];
        float mx = -1e30f;
#pragma unroll
        for (int n = 0; n < 4; n++) { sv[n] = sc4[m][n][j] * 0.125f; mx = fmaxf(mx, sv[n]); }
#pragma unroll
        for (int d = 1; d < 16; d <<= 1) mx = fmaxf(mx, __shfl_xor(mx, d));
        float nm = fmaxf(Mx[m][j], mx);
        float scale = __expf(Mx[m][j] - nm);
        Mx[m][j] = nm;
        float pv[4], ps = 0.f;
#pragma unroll
        for (int n = 0; n < 4; n++) { pv[n] = __expf(sv[n] - nm); ps += pv[n]; }
#pragma unroll
        for (int d = 1; d < 16; d <<= 1) ps += __shfl_xor(ps, d);
        Ls[m][j] = Ls[m][j] * scale + ps;
#pragma unroll
        for (int nn = 0; nn < 4; nn++) accO[m][nn][j] *= scale;
        int prow = m * 16 + lg * 4 + j;
#pragma unroll
        for (int n = 0; n < 4; n++)
          lP[wid][prow * 72 + n * 16 + lr] = f2bf(pv[n]);
      }

    // PV: O += P[32x64] * V[64x64]   (lP is per-wave: in-wave lgkm ordering)
#pragma unroll
    for (int kk = 0; kk < 2; kk++) {
      bf16x8 ap[2];
#pragma unroll
      for (int m = 0; m < 2; m++)
        ap[m] = *(const bf16x8*)&lP[wid][(m * 16 + lr) * 72 + kk * 32 + lg * 8];
#pragma unroll
      for (int nn = 0; nn < 4; nn++) {
        bf16x8 bv = *(const bf16x8*)&lV[(nn * 16 + lr) * 72 + kk * 32 + lg * 8];
#pragma unroll
        for (int m = 0; m < 2; m++)
          accO[m][nn] = __builtin_amdgcn_mfma_f32_16x16x32_bf16(ap[m], bv, accO[m][nn], 0, 0, 0);
      }
    }
    __syncthreads();                            // protect lK/lV for next stage
  }

  int srow0 = qt * 128 + wid * 32;
#pragma unroll
  for (int m = 0; m < 2; m++)
#pragma unroll
    for (int nn = 0; nn < 4; nn++)
#pragma unroll
      for (int j = 0; j < 4; j++) {
        int srow = srow0 + m * 16 + lg * 4 + j;
        float val = accO[m][nn][j] / Ls[m][j];
        o[((size_t)b * S + srow) * E + h * 64 + nn * 16 + lr] = f2bf(val);
      }
}

// ---------------------------------------------------------------------------
extern "C" void kernel_launch(void* const* d_in, const int* in_sizes, int n_in,
                              void* d_out, int out_size, void* d_ws, size_t ws_size,
                              hipStream_t stream) {
  (void)in_sizes; (void)n_in; (void)out_size; (void)ws_size;
  const float* x     = (const float*)d_in[0];
  const float* w_qkv = (const float*)d_in[1];
  const float* w_fc  = (const float*)d_in[2];
  const float* w1    = (const float*)d_in[3];
  const float* b1    = (const float*)d_in[4];
  const float* w2    = (const float*)d_in[5];
  const float* b2    = (const float*)d_in[6];
  float* out = (float*)d_out;
  char* ws = (char*)d_ws;

  // workspace layout (80 MB total)
  u16* wqkvT = (u16*)(ws);                  // [3072][1024] 6 MB
  u16* wfcT  = (u16*)(ws + 6291456);        // [1024][1024] 2 MB
  u16* w1T   = (u16*)(ws + 8388608);        // [4096][1024] 8 MB
  u16* w2T   = (u16*)(ws + 16777216);       // [1024][4096] 8 MB
  u16* hbuf  = (u16*)(ws + 25165824);       // h1 -> attnout -> h2, 8 MB
  u16* qbuf  = (u16*)(ws + 33554432);       // 8 MB
  u16* kbuf  = (u16*)(ws + 41943040);       // 8 MB
  u16* vbuf  = (u16*)(ws + 50331648);       // 8 MB
  u16* vtbuf = (u16*)(ws + 58720256);       // 8 MB
  float* x2  = (float*)(ws + 67108864);     // 16 MB f32
  u16* act   = qbuf;                        // [4096][4096] 32 MB over q..vt (dead)

  wcastT<<<dim3(96, 32), 256, 0, stream>>>(w_qkv, wqkvT, 1024, 3072);
  wcastT<<<dim3(32, 32), 256, 0, stream>>>(w_fc, wfcT, 1024, 1024);
  wcastT<<<dim3(128, 32), 256, 0, stream>>>(w1, w1T, 1024, 4096);
  wcastT<<<dim3(32, 128), 256, 0, stream>>>(w2, w2T, 4096, 1024);

  ln_kernel<<<4096, 256, 0, stream>>>(x, hbuf);
  gemm_bt<0><<<dim3(24, 32), 256, 0, stream>>>(hbuf, wqkvT, 3072, 1024,
                                               nullptr, nullptr, nullptr, qbuf, kbuf, vbuf);
  vtransp<<<dim3(64, 2, 32), 256, 0, stream>>>(vbuf, vtbuf);
  attn_kernel<<<dim3(16, 16, 2), 256, 0, stream>>>(qbuf, kbuf, vtbuf, hbuf);
  gemm_bt<1><<<dim3(8, 32), 256, 0, stream>>>(hbuf, wfcT, 1024, 1024,
                                              x, nullptr, x2, nullptr, nullptr, nullptr);
  ln_kernel<<<4096, 256, 0, stream>>>(x2, hbuf);
  gemm_bt<2><<<dim3(32, 32), 256, 0, stream>>>(hbuf, w1T, 4096, 1024,
                                               nullptr, b1, nullptr, act, nullptr, nullptr);
  gemm_bt<3><<<dim3(8, 32), 256, 0, stream>>>(act, w2T, 1024, 4096,
                                              x2, b2, out, nullptr, nullptr, nullptr);
}

// Round 2
// 350.960 us; speedup vs baseline: 1.0901x; 1.0901x over previous
//
#include <hip/hip_runtime.h>

typedef unsigned short u16;
typedef __attribute__((ext_vector_type(8))) short bf16x8;   // 8 x bf16 (4 VGPRs)
typedef __attribute__((ext_vector_type(4))) short s16x4;
typedef __attribute__((ext_vector_type(4))) float f32x4;

#define DEV __device__ __forceinline__

DEV u16 f2bf(float f) {                       // fp32 -> bf16 bits, RNE
  union { float f; unsigned u; } v; v.f = f;
  unsigned r = v.u + 0x7fffu + ((v.u >> 16) & 1u);
  return (u16)(r >> 16);
}

// async global->LDS, 16B per lane. LDS dest is wave-uniform base; HW adds lane*16.
DEV void gl16(const u16* g, u16* l) {
  __builtin_amdgcn_global_load_lds((const __attribute__((address_space(1))) void*)g,
                                   (__attribute__((address_space(3))) void*)l, 16, 0, 0);
}

// ---- weight cast + transpose: w[K][N] f32 -> wt[N][K] bf16 ----------------
__global__ __launch_bounds__(256) void wcastT(const float* __restrict__ w,
                                              u16* __restrict__ wt, int K, int N) {
  __shared__ float t[32][33];
  int n0 = blockIdx.x * 32, k0 = blockIdx.y * 32;
  int tx = threadIdx.x & 31, ty = threadIdx.x >> 5;
#pragma unroll
  for (int i = 0; i < 32; i += 8)
    t[ty + i][tx] = w[(size_t)(k0 + ty + i) * N + n0 + tx];
  __syncthreads();
#pragma unroll
  for (int i = 0; i < 32; i += 8)
    wt[(size_t)(n0 + ty + i) * K + k0 + tx] = f2bf(t[tx][ty + i]);
}

// ---- V transpose per (b,h): v[s][h*64+d] -> vt[(b*16+h)*64+d][s] ----------
__global__ __launch_bounds__(256) void vtransp(const u16* __restrict__ v,
                                               u16* __restrict__ vt) {
  __shared__ u16 t[32][34];
  int s0 = blockIdx.x * 32, d0 = blockIdx.y * 32;
  int bh = blockIdx.z; int b = bh >> 4, h = bh & 15;
  int tx = threadIdx.x & 31, ty = threadIdx.x >> 5;
#pragma unroll
  for (int i = 0; i < 32; i += 8)
    t[ty + i][tx] = v[(size_t)(b * 2048 + s0 + ty + i) * 1024 + h * 64 + d0 + tx];
  __syncthreads();
#pragma unroll
  for (int i = 0; i < 32; i += 8)
    vt[((size_t)(b * 16 + h) * 64 + d0 + ty + i) * 2048 + s0 + tx] = t[tx][ty + i];
}

// ---- LayerNorm (1024 cols, no affine) f32 -> bf16 -------------------------
__global__ __launch_bounds__(256) void ln_kernel(const float* __restrict__ x,
                                                 u16* __restrict__ out) {
  int row = blockIdx.x, tid = threadIdx.x;
  const float4* xr = (const float4*)(x + (size_t)row * 1024);
  float4 f = xr[tid];
  float s = f.x + f.y + f.z + f.w;
  float s2 = f.x * f.x + f.y * f.y + f.z * f.z + f.w * f.w;
#pragma unroll
  for (int o = 1; o < 64; o <<= 1) { s += __shfl_xor(s, o); s2 += __shfl_xor(s2, o); }
  __shared__ float red[2][4];
  int wid = tid >> 6;
  if ((tid & 63) == 0) { red[0][wid] = s; red[1][wid] = s2; }
  __syncthreads();
  float tot  = red[0][0] + red[0][1] + red[0][2] + red[0][3];
  float tot2 = red[1][0] + red[1][1] + red[1][2] + red[1][3];
  float mu = tot * (1.0f / 1024.0f);
  float var = tot2 * (1.0f / 1024.0f) - mu * mu;
  float rstd = rsqrtf(var + 1e-5f);
  s16x4 o4;
  o4[0] = (short)f2bf((f.x - mu) * rstd);
  o4[1] = (short)f2bf((f.y - mu) * rstd);
  o4[2] = (short)f2bf((f.z - mu) * rstd);
  o4[3] = (short)f2bf((f.w - mu) * rstd);
  *(s16x4*)(out + (size_t)row * 1024 + tid * 4) = o4;
}

// ---- GEMM: C[M,N] = A[M,K](bf16) * Bt[N,K]^T(bf16), fused epilogues -------
// m97 structure: BMx128 tile, BK=32, global_load_lds width 16, linear LDS.
// 4 waves, wave tile (BM/2)x64. BM in {64,128}.
// MODE 0: qkv split -> o0/o1/o2 bf16    MODE 1: outF = resid + C (f32)
// MODE 2: o0 = gelu(C + bias) bf16      MODE 3: outF = resid + bias + C (f32)
template <int MODE, int BM>
__global__ __launch_bounds__(256) void gemm_bt(
    const u16* __restrict__ A, const u16* __restrict__ Bt, int N, int K,
    const float* __restrict__ resid, const float* __restrict__ bias,
    float* __restrict__ outF, u16* __restrict__ o0, u16* __restrict__ o1,
    u16* __restrict__ o2) {
  constexpr int MR = BM / 32;                   // acc m-tiles per wave
  __shared__ __align__(16) u16 lA[BM * 32];     // linear: required by global_load_lds
  __shared__ __align__(16) u16 lB[128 * 32];
  int tid = threadIdx.x;
  int lane = tid & 63, wid = tid >> 6;
  int lr = lane & 15, lg = lane >> 4;
  int rowBase = blockIdx.y * BM, colBase = blockIdx.x * 128;
  int wr = (wid >> 1) * (MR * 16), wc = (wid & 1) * 64;

  // staging: one call round = 256 lanes x 16B = 64 rows x 64B; wave wid covers
  // rows [c*64 + wid*16, +16), lane l -> row +(l>>2), col u16 (l&3)*8.
  int srow = wid * 16 + (lane >> 2);
  int scol = (lane & 3) * 8;
  const u16* gA = A + (size_t)(rowBase + srow) * K + scol;
  const u16* gB = Bt + (size_t)(colBase + srow) * K + scol;
  u16* lAb = &lA[wid * 16 * 32];                // wave-uniform base
  u16* lBb = &lB[wid * 16 * 32];

  f32x4 acc[MR][4];
  f32x4 zero = {0.f, 0.f, 0.f, 0.f};
#pragma unroll
  for (int m = 0; m < MR; m++)
#pragma unroll
    for (int n = 0; n < 4; n++) acc[m][n] = zero;

  for (int k0 = 0; k0 < K; k0 += 32) {
    __syncthreads();                            // prior iter's frag reads done
#pragma unroll
    for (int c = 0; c < BM / 64; c++)
      gl16(gA + (size_t)c * 64 * K + k0, lAb + c * 64 * 32);
#pragma unroll
    for (int c = 0; c < 2; c++)
      gl16(gB + (size_t)c * 64 * K + k0, lBb + c * 64 * 32);
    __syncthreads();                            // compiler drains vmcnt here
    bf16x8 af[MR], bfv[4];
#pragma unroll
    for (int m = 0; m < MR; m++)
      af[m] = *(const bf16x8*)&lA[(wr + m * 16 + lr) * 32 + lg * 8];
#pragma unroll
    for (int n = 0; n < 4; n++)
      bfv[n] = *(const bf16x8*)&lB[(wc + n * 16 + lr) * 32 + lg * 8];
#pragma unroll
    for (int m = 0; m < MR; m++)
#pragma unroll
      for (int n = 0; n < 4; n++)
        acc[m][n] = __builtin_amdgcn_mfma_f32_16x16x32_bf16(af[m], bfv[n], acc[m][n], 0, 0, 0);
  }

#pragma unroll
  for (int m = 0; m < MR; m++) {
    int grow0 = rowBase + wr + m * 16 + lg * 4;
#pragma unroll
    for (int n = 0; n < 4; n++) {
      int gcol = colBase + wc + n * 16 + lr;
#pragma unroll
      for (int j = 0; j < 4; j++) {
        int grow = grow0 + j;
        float val = acc[m][n][j];
        if constexpr (MODE == 0) {
          u16* dst = (gcol < 1024) ? o0 : ((gcol < 2048) ? o1 : o2);
          dst[(size_t)grow * 1024 + (gcol & 1023)] = f2bf(val);
        } else if constexpr (MODE == 1) {
          size_t idx = (size_t)grow * N + gcol;
          outF[idx] = resid[idx] + val;
        } else if constexpr (MODE == 2) {
          float g = val + bias[gcol];
          float c3 = 0.7978845608028654f * (g + 0.044715f * g * g * g);
          o0[(size_t)grow * N + gcol] = f2bf(0.5f * g * (1.0f + tanhf(c3)));
        } else {
          size_t idx = (size_t)grow * N + gcol;
          outF[idx] = resid[idx] + bias[gcol] + val;
        }
      }
    }
  }
}

// ---- Flash attention: block = (b, h, 64 q-rows); 4 waves x 16 rows --------
// Single-buffered LDS + T14 issue-early/write-late reg prefetch.
__global__ __launch_bounds__(256) void attn_kernel(const u16* __restrict__ q,
                                                   const u16* __restrict__ k,
                                                   const u16* __restrict__ vt,
                                                   u16* __restrict__ o) {
  __shared__ __align__(16) u16 lK[64 * 72];     // [kv][d] pad->72
  __shared__ __align__(16) u16 lV[64 * 72];     // [d][kv] pad->72
  __shared__ __align__(16) u16 lP[4][16 * 72];  // per-wave P re-layout
  const int S = 2048, E = 1024;
  int qt = blockIdx.x, h = blockIdx.y, b = blockIdx.z;
  int tid = threadIdx.x, wid = tid >> 6, lane = tid & 63;
  int lr = lane & 15, lg = lane >> 4;

  const u16* qp = q + ((size_t)b * S + qt * 64 + wid * 16) * E + h * 64;
  const u16* kp = k + (size_t)b * S * E + h * 64;
  const u16* vp = vt + ((size_t)(b * 16 + h) * 64) * S;

  bf16x8 aQ[2];                                 // Q hoisted to registers
#pragma unroll
  for (int kk = 0; kk < 2; kk++)
    aQ[kk] = *(const bf16x8*)(qp + (size_t)lr * E + kk * 32 + lg * 8);

  f32x4 accO[4];
  float Mx[4], Ls[4];
  f32x4 zero = {0.f, 0.f, 0.f, 0.f};
#pragma unroll
  for (int j = 0; j < 4; j++) { Mx[j] = -1e30f; Ls[j] = 0.f; }
#pragma unroll
  for (int nn = 0; nn < 4; nn++) accO[nn] = zero;

  int sr_ = tid >> 3, sc_ = (tid & 7) * 8;      // staging: 32 rows x 64 cols / pass
  const u16* kps0 = kp + (size_t)sr_ * E + sc_;
  const u16* kps1 = kp + (size_t)(sr_ + 32) * E + sc_;
  const u16* vps0 = vp + (size_t)sr_ * S + sc_;
  const u16* vps1 = vp + (size_t)(sr_ + 32) * S + sc_;

  bf16x8 rk0 = *(const bf16x8*)(kps0);          // prologue: tile 0 -> regs
  bf16x8 rk1 = *(const bf16x8*)(kps1);
  bf16x8 rv0 = *(const bf16x8*)(vps0);
  bf16x8 rv1 = *(const bf16x8*)(vps1);

  for (int kv0 = 0; kv0 < S; kv0 += 64) {
    __syncthreads();                            // prior tile fully consumed
    *(bf16x8*)&lK[sr_ * 72 + sc_] = rk0;
    *(bf16x8*)&lK[(32 + sr_) * 72 + sc_] = rk1;
    *(bf16x8*)&lV[sr_ * 72 + sc_] = rv0;
    *(bf16x8*)&lV[(32 + sr_) * 72 + sc_] = rv1;
    int nx = kv0 + 64;
    if (nx < S) {                               // issue-early: next tile -> regs
      rk0 = *(const bf16x8*)(kps0 + (size_t)nx * E);
      rk1 = *(const bf16x8*)(kps1 + (size_t)nx * E);
      rv0 = *(const bf16x8*)(vps0 + nx);
      rv1 = *(const bf16x8*)(vps1 + nx);
    }
    __syncthreads();                            // lK/lV visible; loads in flight

    // QK^T: S[q 16][kv 64]
    f32x4 sc4[4];
#pragma unroll
    for (int n = 0; n < 4; n++) sc4[n] = zero;
#pragma unroll
    for (int n = 0; n < 4; n++) {
      bf16x8 bk0 = *(const bf16x8*)&lK[(n * 16 + lr) * 72 + lg * 8];
      bf16x8 bk1 = *(const bf16x8*)&lK[(n * 16 + lr) * 72 + 32 + lg * 8];
      sc4[n] = __builtin_amdgcn_mfma_f32_16x16x32_bf16(aQ[0], bk0, sc4[n], 0, 0, 0);
      sc4[n] = __builtin_amdgcn_mfma_f32_16x16x32_bf16(aQ[1], bk1, sc4[n], 0, 0, 0);
    }

    // online softmax per q-row (wave-parallel over the 16-lane col groups)
#pragma unroll
    for (int j = 0; j < 4; j++) {
      float sv[4];
      float mx = -1e30f;
#pragma unroll
      for (int n = 0; n < 4; n++) { sv[n] = sc4[n][j] * 0.125f; mx = fmaxf(mx, sv[n]); }
#pragma unroll
      for (int d = 1; d < 16; d <<= 1) mx = fmaxf(mx, __shfl_xor(mx, d));
      float nm = fmaxf(Mx[j], mx);
      float scale = __expf(Mx[j] - nm);
      Mx[j] = nm;
      float pv[4], ps = 0.f;
#pragma unroll
      for (int n = 0; n < 4; n++) { pv[n] = __expf(sv[n] - nm); ps += pv[n]; }
#pragma unroll
      for (int d = 1; d < 16; d <<= 1) ps += __shfl_xor(ps, d);
      Ls[j] = Ls[j] * scale + ps;
#pragma unroll
      for (int nn = 0; nn < 4; nn++) accO[nn][j] *= scale;
      int prow = lg * 4 + j;
#pragma unroll
      for (int n = 0; n < 4; n++)
        lP[wid][prow * 72 + n * 16 + lr] = f2bf(pv[n]);
    }

    // PV: O += P[16x64] * V[64x64]   (lP per-wave: in-wave lgkm ordering)
#pragma unroll
    for (int kk = 0; kk < 2; kk++) {
      bf16x8 ap = *(const bf16x8*)&lP[wid][lr * 72 + kk * 32 + lg * 8];
#pragma unroll
      for (int nn = 0; nn < 4; nn++) {
        bf16x8 bv = *(const bf16x8*)&lV[(nn * 16 + lr) * 72 + kk * 32 + lg * 8];
        accO[nn] = __builtin_amdgcn_mfma_f32_16x16x32_bf16(ap, bv, accO[nn], 0, 0, 0);
      }
    }
  }

  int srow0 = qt * 64 + wid * 16;
#pragma unroll
  for (int nn = 0; nn < 4; nn++)
#pragma unroll
    for (int j = 0; j < 4; j++) {
      int srow = srow0 + lg * 4 + j;
      float val = accO[nn][j] / Ls[j];
      o[((size_t)b * S + srow) * E + h * 64 + nn * 16 + lr] = f2bf(val);
    }
}

// ---------------------------------------------------------------------------
extern "C" void kernel_launch(void* const* d_in, const int* in_sizes, int n_in,
                              void* d_out, int out_size, void* d_ws, size_t ws_size,
                              hipStream_t stream) {
  (void)in_sizes; (void)n_in; (void)out_size; (void)ws_size;
  const float* x     = (const float*)d_in[0];
  const float* w_qkv = (const float*)d_in[1];
  const float* w_fc  = (const float*)d_in[2];
  const float* w1    = (const float*)d_in[3];
  const float* b1    = (const float*)d_in[4];
  const float* w2    = (const float*)d_in[5];
  const float* b2    = (const float*)d_in[6];
  float* out = (float*)d_out;
  char* ws = (char*)d_ws;

  // workspace layout (80 MB total)
  u16* wqkvT = (u16*)(ws);                  // [3072][1024] 6 MB
  u16* wfcT  = (u16*)(ws + 6291456);        // [1024][1024] 2 MB
  u16* w1T   = (u16*)(ws + 8388608);        // [4096][1024] 8 MB
  u16* w2T   = (u16*)(ws + 16777216);       // [1024][4096] 8 MB
  u16* hbuf  = (u16*)(ws + 25165824);       // h1 -> attnout -> h2, 8 MB
  u16* qbuf  = (u16*)(ws + 33554432);       // 8 MB
  u16* kbuf  = (u16*)(ws + 41943040);       // 8 MB
  u16* vbuf  = (u16*)(ws + 50331648);       // 8 MB
  u16* vtbuf = (u16*)(ws + 58720256);       // 8 MB
  float* x2  = (float*)(ws + 67108864);     // 16 MB f32
  u16* act   = qbuf;                        // [4096][4096] 32 MB over q..vt (dead)

  wcastT<<<dim3(96, 32), 256, 0, stream>>>(w_qkv, wqkvT, 1024, 3072);
  wcastT<<<dim3(32, 32), 256, 0, stream>>>(w_fc, wfcT, 1024, 1024);
  wcastT<<<dim3(128, 32), 256, 0, stream>>>(w1, w1T, 1024, 4096);
  wcastT<<<dim3(32, 128), 256, 0, stream>>>(w2, w2T, 4096, 1024);

  ln_kernel<<<4096, 256, 0, stream>>>(x, hbuf);
  gemm_bt<0, 128><<<dim3(24, 32), 256, 0, stream>>>(hbuf, wqkvT, 3072, 1024,
                                                    nullptr, nullptr, nullptr, qbuf, kbuf, vbuf);
  vtransp<<<dim3(64, 2, 32), 256, 0, stream>>>(vbuf, vtbuf);
  attn_kernel<<<dim3(32, 16, 2), 256, 0, stream>>>(qbuf, kbuf, vtbuf, hbuf);
  gemm_bt<1, 64><<<dim3(8, 64), 256, 0, stream>>>(hbuf, wfcT, 1024, 1024,
                                                  x, nullptr, x2, nullptr, nullptr, nullptr);
  ln_kernel<<<4096, 256, 0, stream>>>(x2, hbuf);
  gemm_bt<2, 128><<<dim3(32, 32), 256, 0, stream>>>(hbuf, w1T, 4096, 1024,
                                                    nullptr, b1, nullptr, act, nullptr, nullptr);
  gemm_bt<3, 64><<<dim3(8, 64), 256, 0, stream>>>(act, w2T, 1024, 4096,
                                                  x2, b2, out, nullptr, nullptr, nullptr);
}

// Round 3
// 338.673 us; speedup vs baseline: 1.1296x; 1.0363x over previous
//
#include <hip/hip_runtime.h>

typedef unsigned short u16;
typedef __attribute__((ext_vector_type(8))) short bf16x8;   // 8 x bf16 (4 VGPRs)
typedef __attribute__((ext_vector_type(4))) short s16x4;
typedef __attribute__((ext_vector_type(4))) float f32x4;

#define DEV __device__ __forceinline__

DEV u16 f2bf(float f) {                       // fp32 -> bf16 bits, RNE
  union { float f; unsigned u; } v; v.f = f;
  unsigned r = v.u + 0x7fffu + ((v.u >> 16) & 1u);
  return (u16)(r >> 16);
}
DEV u16 f2bf_tr(float f) {                    // truncating (P only; bias cancels in O/l)
  union { float f; unsigned u; } v; v.f = f;
  return (u16)(v.u >> 16);
}

// XOR bank-swizzle for a 64-col bf16 LDS tile (u16 index units).
// byte ^= (row&7)<<4  ==  u16col ^= (row&7)<<3. Keeps 16B alignment of 8-col chunks.
DEV int swzi(int row, int col) { return row * 64 + (col ^ ((row & 7) << 3)); }

// async global->LDS, 16B per lane. LDS dest is wave-uniform base; HW adds lane*16.
DEV void gl16(const u16* g, u16* l) {
  __builtin_amdgcn_global_load_lds((const __attribute__((address_space(1))) void*)g,
                                   (__attribute__((address_space(3))) void*)l, 16, 0, 0);
}

// ---- weight cast + transpose: w[K][N] f32 -> wt[N][K] bf16 ----------------
__global__ __launch_bounds__(256) void wcastT(const float* __restrict__ w,
                                              u16* __restrict__ wt, int K, int N) {
  __shared__ float t[32][33];
  int n0 = blockIdx.x * 32, k0 = blockIdx.y * 32;
  int tx = threadIdx.x & 31, ty = threadIdx.x >> 5;
#pragma unroll
  for (int i = 0; i < 32; i += 8)
    t[ty + i][tx] = w[(size_t)(k0 + ty + i) * N + n0 + tx];
  __syncthreads();
#pragma unroll
  for (int i = 0; i < 32; i += 8)
    wt[(size_t)(n0 + ty + i) * K + k0 + tx] = f2bf(t[tx][ty + i]);
}

// ---- V transpose per (b,h): v[s][h*64+d] -> vt[(b*16+h)*64+d][s] ----------
__global__ __launch_bounds__(256) void vtransp(const u16* __restrict__ v,
                                               u16* __restrict__ vt) {
  __shared__ u16 t[32][34];
  int s0 = blockIdx.x * 32, d0 = blockIdx.y * 32;
  int bh = blockIdx.z; int b = bh >> 4, h = bh & 15;
  int tx = threadIdx.x & 31, ty = threadIdx.x >> 5;
#pragma unroll
  for (int i = 0; i < 32; i += 8)
    t[ty + i][tx] = v[(size_t)(b * 2048 + s0 + ty + i) * 1024 + h * 64 + d0 + tx];
  __syncthreads();
#pragma unroll
  for (int i = 0; i < 32; i += 8)
    vt[((size_t)(b * 16 + h) * 64 + d0 + ty + i) * 2048 + s0 + tx] = t[tx][ty + i];
}

// ---- LayerNorm (1024 cols, no affine) f32 -> bf16 -------------------------
__global__ __launch_bounds__(256) void ln_kernel(const float* __restrict__ x,
                                                 u16* __restrict__ out) {
  int row = blockIdx.x, tid = threadIdx.x;
  const float4* xr = (const float4*)(x + (size_t)row * 1024);
  float4 f = xr[tid];
  float s = f.x + f.y + f.z + f.w;
  float s2 = f.x * f.x + f.y * f.y + f.z * f.z + f.w * f.w;
#pragma unroll
  for (int o = 1; o < 64; o <<= 1) { s += __shfl_xor(s, o); s2 += __shfl_xor(s2, o); }
  __shared__ float red[2][4];
  int wid = tid >> 6;
  if ((tid & 63) == 0) { red[0][wid] = s; red[1][wid] = s2; }
  __syncthreads();
  float tot  = red[0][0] + red[0][1] + red[0][2] + red[0][3];
  float tot2 = red[1][0] + red[1][1] + red[1][2] + red[1][3];
  float mu = tot * (1.0f / 1024.0f);
  float var = tot2 * (1.0f / 1024.0f) - mu * mu;
  float rstd = rsqrtf(var + 1e-5f);
  s16x4 o4;
  o4[0] = (short)f2bf((f.x - mu) * rstd);
  o4[1] = (short)f2bf((f.y - mu) * rstd);
  o4[2] = (short)f2bf((f.z - mu) * rstd);
  o4[3] = (short)f2bf((f.w - mu) * rstd);
  *(s16x4*)(out + (size_t)row * 1024 + tid * 4) = o4;
}

// ---- GEMM: C[M,N] = A[M,K](bf16) * Bt[N,K]^T(bf16), fused epilogues -------
// m97 structure: BMx128 tile, BK=32, global_load_lds width 16, linear LDS.
// MODE 0: qkv split -> o0/o1/o2 bf16 (q pre-scaled by 0.125*log2e for attn)
// MODE 1: outF = resid + C (f32)
// MODE 2: o0 = gelu(C + bias) bf16      MODE 3: outF = resid + bias + C (f32)
template <int MODE, int BM>
__global__ __launch_bounds__(256) void gemm_bt(
    const u16* __restrict__ A, const u16* __restrict__ Bt, int N, int K,
    const float* __restrict__ resid, const float* __restrict__ bias,
    float* __restrict__ outF, u16* __restrict__ o0, u16* __restrict__ o1,
    u16* __restrict__ o2) {
  constexpr int MR = BM / 32;                   // acc m-tiles per wave
  __shared__ __align__(16) u16 lA[BM * 32];     // linear: required by global_load_lds
  __shared__ __align__(16) u16 lB[128 * 32];
  int tid = threadIdx.x;
  int lane = tid & 63, wid = tid >> 6;
  int lr = lane & 15, lg = lane >> 4;
  int rowBase = blockIdx.y * BM, colBase = blockIdx.x * 128;
  int wr = (wid >> 1) * (MR * 16), wc = (wid & 1) * 64;

  int srow = wid * 16 + (lane >> 2);
  int scol = (lane & 3) * 8;
  const u16* gA = A + (size_t)(rowBase + srow) * K + scol;
  const u16* gB = Bt + (size_t)(colBase + srow) * K + scol;
  u16* lAb = &lA[wid * 16 * 32];                // wave-uniform base
  u16* lBb = &lB[wid * 16 * 32];

  f32x4 acc[MR][4];
  f32x4 zero = {0.f, 0.f, 0.f, 0.f};
#pragma unroll
  for (int m = 0; m < MR; m++)
#pragma unroll
    for (int n = 0; n < 4; n++) acc[m][n] = zero;

  for (int k0 = 0; k0 < K; k0 += 32) {
    __syncthreads();                            // prior iter's frag reads done
#pragma unroll
    for (int c = 0; c < BM / 64; c++)
      gl16(gA + (size_t)c * 64 * K + k0, lAb + c * 64 * 32);
#pragma unroll
    for (int c = 0; c < 2; c++)
      gl16(gB + (size_t)c * 64 * K + k0, lBb + c * 64 * 32);
    __syncthreads();                            // compiler drains vmcnt here
    bf16x8 af[MR], bfv[4];
#pragma unroll
    for (int m = 0; m < MR; m++)
      af[m] = *(const bf16x8*)&lA[(wr + m * 16 + lr) * 32 + lg * 8];
#pragma unroll
    for (int n = 0; n < 4; n++)
      bfv[n] = *(const bf16x8*)&lB[(wc + n * 16 + lr) * 32 + lg * 8];
#pragma unroll
    for (int m = 0; m < MR; m++)
#pragma unroll
      for (int n = 0; n < 4; n++)
        acc[m][n] = __builtin_amdgcn_mfma_f32_16x16x32_bf16(af[m], bfv[n], acc[m][n], 0, 0, 0);
  }

#pragma unroll
  for (int m = 0; m < MR; m++) {
    int grow0 = rowBase + wr + m * 16 + lg * 4;
#pragma unroll
    for (int n = 0; n < 4; n++) {
      int gcol = colBase + wc + n * 16 + lr;
#pragma unroll
      for (int j = 0; j < 4; j++) {
        int grow = grow0 + j;
        float val = acc[m][n][j];
        if constexpr (MODE == 0) {
          u16* dst = (gcol < 1024) ? o0 : ((gcol < 2048) ? o1 : o2);
          float v2 = (gcol < 1024) ? val * 0.18033688011112042f : val;  // q: /8 * log2e
          dst[(size_t)grow * 1024 + (gcol & 1023)] = f2bf(v2);
        } else if constexpr (MODE == 1) {
          size_t idx = (size_t)grow * N + gcol;
          outF[idx] = resid[idx] + val;
        } else if constexpr (MODE == 2) {
          float g = val + bias[gcol];
          float c3 = 0.7978845608028654f * (g + 0.044715f * g * g * g);
          o0[(size_t)grow * N + gcol] = f2bf(0.5f * g * (1.0f + tanhf(c3)));
        } else {
          size_t idx = (size_t)grow * N + gcol;
          outF[idx] = resid[idx] + bias[gcol] + val;
        }
      }
    }
  }
}

// ---- Flash attention: block = (b, h, 64 q-rows); 4 waves x 16 rows --------
// Scores arrive in exp2-domain (Q pre-scaled). Ones-MFMA row-sum, defer-max,
// trunc-bf16 P, XOR-swizzled LDS, T14 issue-early/write-late prefetch.
__global__ __launch_bounds__(256) void attn_kernel(const u16* __restrict__ q,
                                                   const u16* __restrict__ k,
                                                   const u16* __restrict__ vt,
                                                   u16* __restrict__ o) {
  __shared__ __align__(16) u16 lK[64 * 64];     // [kv][d], swizzled
  __shared__ __align__(16) u16 lV[64 * 64];     // [d][kv], swizzled
  __shared__ __align__(16) u16 lP[4 * 16 * 64]; // per-wave P, swizzled
  const int S = 2048, E = 1024;
  int qt = blockIdx.x, h = blockIdx.y, b = blockIdx.z;
  int tid = threadIdx.x, wid = tid >> 6, lane = tid & 63;
  int lr = lane & 15, lg = lane >> 4;
  u16* lPw = &lP[wid * 16 * 64];

  const u16* qp = q + ((size_t)b * S + qt * 64 + wid * 16) * E + h * 64;
  const u16* kp = k + (size_t)b * S * E + h * 64;
  const u16* vp = vt + ((size_t)(b * 16 + h) * 64) * S;

  bf16x8 aQ[2];                                 // Q hoisted to registers
#pragma unroll
  for (int kk = 0; kk < 2; kk++)
    aQ[kk] = *(const bf16x8*)(qp + (size_t)lr * E + kk * 32 + lg * 8);

  bf16x8 onesv;                                 // B-fragment of all 1.0 (bf16)
#pragma unroll
  for (int i = 0; i < 8; i++) onesv[i] = (short)0x3F80;

  f32x4 accO[4], accL;
  float Mx[4];
  f32x4 zero = {0.f, 0.f, 0.f, 0.f};
  accL = zero;
#pragma unroll
  for (int j = 0; j < 4; j++) Mx[j] = -1e30f;
#pragma unroll
  for (int nn = 0; nn < 4; nn++) accO[nn] = zero;

  int sr_ = tid >> 3, sc_ = (tid & 7) * 8;      // staging: 32 rows x 64 cols / pass
  const u16* kps0 = kp + (size_t)sr_ * E + sc_;
  const u16* kps1 = kp + (size_t)(sr_ + 32) * E + sc_;
  const u16* vps0 = vp + (size_t)sr_ * S + sc_;
  const u16* vps1 = vp + (size_t)(sr_ + 32) * S + sc_;

  bf16x8 rk0 = *(const bf16x8*)(kps0);          // prologue: tile 0 -> regs
  bf16x8 rk1 = *(const bf16x8*)(kps1);
  bf16x8 rv0 = *(const bf16x8*)(vps0);
  bf16x8 rv1 = *(const bf16x8*)(vps1);

  for (int kv0 = 0; kv0 < S; kv0 += 64) {
    __syncthreads();                            // prior tile fully consumed
    *(bf16x8*)&lK[swzi(sr_, sc_)] = rk0;
    *(bf16x8*)&lK[swzi(32 + sr_, sc_)] = rk1;
    *(bf16x8*)&lV[swzi(sr_, sc_)] = rv0;
    *(bf16x8*)&lV[swzi(32 + sr_, sc_)] = rv1;
    int nx = kv0 + 64;
    if (nx < S) {                               // issue-early: next tile -> regs
      rk0 = *(const bf16x8*)(kps0 + (size_t)nx * E);
      rk1 = *(const bf16x8*)(kps1 + (size_t)nx * E);
      rv0 = *(const bf16x8*)(vps0 + nx);
      rv1 = *(const bf16x8*)(vps1 + nx);
    }
    __syncthreads();                            // lK/lV visible; loads in flight

    // QK^T: S[q 16][kv 64] (exp2-domain scores; Q pre-scaled)
    f32x4 sc4[4];
#pragma unroll
    for (int n = 0; n < 4; n++) sc4[n] = zero;
#pragma unroll
    for (int n = 0; n < 4; n++) {
      bf16x8 bk0 = *(const bf16x8*)&lK[swzi(n * 16 + lr, lg * 8)];
      bf16x8 bk1 = *(const bf16x8*)&lK[swzi(n * 16 + lr, 32 + lg * 8)];
      sc4[n] = __builtin_amdgcn_mfma_f32_16x16x32_bf16(aQ[0], bk0, sc4[n], 0, 0, 0);
      sc4[n] = __builtin_amdgcn_mfma_f32_16x16x32_bf16(aQ[1], bk1, sc4[n], 0, 0, 0);
    }

    // row max (wave-parallel over 16-lane col groups)
    float mxr[4];
#pragma unroll
    for (int j = 0; j < 4; j++) {
      float mx = fmaxf(fmaxf(sc4[0][j], sc4[1][j]), fmaxf(sc4[2][j], sc4[3][j]));
#pragma unroll
      for (int d = 1; d < 16; d <<= 1) mx = fmaxf(mx, __shfl_xor(mx, d));
      mxr[j] = mx;
    }
    // defer-max: rescale only when some row grew > 8 (in log2 domain)
    bool need = (mxr[0] > Mx[0] + 8.f) || (mxr[1] > Mx[1] + 8.f) ||
                (mxr[2] > Mx[2] + 8.f) || (mxr[3] > Mx[3] + 8.f);
    if (__any(need)) {
#pragma unroll
      for (int j = 0; j < 4; j++) {
        float nm = fmaxf(Mx[j], mxr[j]);
        float s = __builtin_amdgcn_exp2f(Mx[j] - nm);
        Mx[j] = nm;
        accL[j] *= s;
#pragma unroll
        for (int nn = 0; nn < 4; nn++) accO[nn][j] *= s;
      }
    }
    // P = exp2(S - Mx), trunc-bf16, to per-wave swizzled LDS
#pragma unroll
    for (int j = 0; j < 4; j++) {
      int prow = lg * 4 + j;
#pragma unroll
      for (int n = 0; n < 4; n++) {
        float p = __builtin_amdgcn_exp2f(sc4[n][j] - Mx[j]);
        lPw[swzi(prow, n * 16 + lr)] = f2bf_tr(p);
      }
    }

    // PV: O += P[16x64] * V[64x64]; l += P * ones (in-wave lgkm ordering)
#pragma unroll
    for (int kk = 0; kk < 2; kk++) {
      bf16x8 ap = *(const bf16x8*)&lPw[swzi(lr, kk * 32 + lg * 8)];
      accL = __builtin_amdgcn_mfma_f32_16x16x32_bf16(ap, onesv, accL, 0, 0, 0);
#pragma unroll
      for (int nn = 0; nn < 4; nn++) {
        bf16x8 bv = *(const bf16x8*)&lV[swzi(nn * 16 + lr, kk * 32 + lg * 8)];
        accO[nn] = __builtin_amdgcn_mfma_f32_16x16x32_bf16(ap, bv, accO[nn], 0, 0, 0);
      }
    }
  }

  int srow0 = qt * 64 + wid * 16;
#pragma unroll
  for (int j = 0; j < 4; j++) {
    float inv = 1.0f / accL[j];
    int srow = srow0 + lg * 4 + j;
#pragma unroll
    for (int nn = 0; nn < 4; nn++)
      o[((size_t)b * S + srow) * E + h * 64 + nn * 16 + lr] = f2bf(accO[nn][j] * inv);
  }
}

// ---------------------------------------------------------------------------
extern "C" void kernel_launch(void* const* d_in, const int* in_sizes, int n_in,
                              void* d_out, int out_size, void* d_ws, size_t ws_size,
                              hipStream_t stream) {
  (void)in_sizes; (void)n_in; (void)out_size; (void)ws_size;
  const float* x     = (const float*)d_in[0];
  const float* w_qkv = (const float*)d_in[1];
  const float* w_fc  = (const float*)d_in[2];
  const float* w1    = (const float*)d_in[3];
  const float* b1    = (const float*)d_in[4];
  const float* w2    = (const float*)d_in[5];
  const float* b2    = (const float*)d_in[6];
  float* out = (float*)d_out;
  char* ws = (char*)d_ws;

  // workspace layout (80 MB total)
  u16* wqkvT = (u16*)(ws);                  // [3072][1024] 6 MB
  u16* wfcT  = (u16*)(ws + 6291456);        // [1024][1024] 2 MB
  u16* w1T   = (u16*)(ws + 8388608);        // [4096][1024] 8 MB
  u16* w2T   = (u16*)(ws + 16777216);       // [1024][4096] 8 MB
  u16* hbuf  = (u16*)(ws + 25165824);       // h1 -> attnout -> h2, 8 MB
  u16* qbuf  = (u16*)(ws + 33554432);       // 8 MB
  u16* kbuf  = (u16*)(ws + 41943040);       // 8 MB
  u16* vbuf  = (u16*)(ws + 50331648);       // 8 MB
  u16* vtbuf = (u16*)(ws + 58720256);       // 8 MB
  float* x2  = (float*)(ws + 67108864);     // 16 MB f32
  u16* act   = qbuf;                        // [4096][4096] 32 MB over q..vt (dead)

  wcastT<<<dim3(96, 32), 256, 0, stream>>>(w_qkv, wqkvT, 1024, 3072);
  wcastT<<<dim3(32, 32), 256, 0, stream>>>(w_fc, wfcT, 1024, 1024);
  wcastT<<<dim3(128, 32), 256, 0, stream>>>(w1, w1T, 1024, 4096);
  wcastT<<<dim3(32, 128), 256, 0, stream>>>(w2, w2T, 4096, 1024);

  ln_kernel<<<4096, 256, 0, stream>>>(x, hbuf);
  gemm_bt<0, 128><<<dim3(24, 32), 256, 0, stream>>>(hbuf, wqkvT, 3072, 1024,
                                                    nullptr, nullptr, nullptr, qbuf, kbuf, vbuf);
  vtransp<<<dim3(64, 2, 32), 256, 0, stream>>>(vbuf, vtbuf);
  attn_kernel<<<dim3(32, 16, 2), 256, 0, stream>>>(qbuf, kbuf, vtbuf, hbuf);
  gemm_bt<1, 64><<<dim3(8, 64), 256, 0, stream>>>(hbuf, wfcT, 1024, 1024,
                                                  x, nullptr, x2, nullptr, nullptr, nullptr);
  ln_kernel<<<4096, 256, 0, stream>>>(x2, hbuf);
  gemm_bt<2, 128><<<dim3(32, 32), 256, 0, stream>>>(hbuf, w1T, 4096, 1024,
                                                    nullptr, b1, nullptr, act, nullptr, nullptr);
  gemm_bt<3, 64><<<dim3(8, 64), 256, 0, stream>>>(act, w2T, 1024, 4096,
                                                  x2, b2, out, nullptr, nullptr, nullptr);
}

// Round 4
// 293.278 us; speedup vs baseline: 1.3045x; 1.1548x over previous
//
#include <hip/hip_runtime.h>

typedef unsigned short u16;
typedef __attribute__((ext_vector_type(8))) short bf16x8;   // 8 x bf16 (4 VGPRs)
typedef __attribute__((ext_vector_type(4))) short s16x4;
typedef __attribute__((ext_vector_type(4))) float f32x4;

#define DEV __device__ __forceinline__

DEV u16 f2bf(float f) {                       // fp32 -> bf16 bits, RNE
  union { float f; unsigned u; } v; v.f = f;
  unsigned r = v.u + 0x7fffu + ((v.u >> 16) & 1u);
  return (u16)(r >> 16);
}
DEV u16 f2bf_tr(float f) {                    // truncating (P only; bias cancels in O/l)
  union { float f; unsigned u; } v; v.f = f;
  return (u16)(v.u >> 16);
}

// XOR bank-swizzle for a 64-col bf16 LDS tile (u16 index units).
// byte ^= (row&7)<<4  ==  u16col ^= (row&7)<<3. Keeps 16B alignment of 8-chunks
// and 8B alignment of 4-chunks (XOR touches bits 3..5 only).
DEV int swzi(int row, int col) { return row * 64 + (col ^ ((row & 7) << 3)); }

// async global->LDS, 16B per lane. LDS dest is wave-uniform base; HW adds lane*16.
DEV void gl16(const u16* g, u16* l) {
  __builtin_amdgcn_global_load_lds((const __attribute__((address_space(1))) void*)g,
                                   (__attribute__((address_space(3))) void*)l, 16, 0, 0);
}

// ---- weight cast + transpose: w[K][N] f32 -> wt[N][K] bf16 ----------------
__global__ __launch_bounds__(256) void wcastT(const float* __restrict__ w,
                                              u16* __restrict__ wt, int K, int N) {
  __shared__ float t[32][33];
  int n0 = blockIdx.x * 32, k0 = blockIdx.y * 32;
  int tx = threadIdx.x & 31, ty = threadIdx.x >> 5;
#pragma unroll
  for (int i = 0; i < 32; i += 8)
    t[ty + i][tx] = w[(size_t)(k0 + ty + i) * N + n0 + tx];
  __syncthreads();
#pragma unroll
  for (int i = 0; i < 32; i += 8)
    wt[(size_t)(n0 + ty + i) * K + k0 + tx] = f2bf(t[tx][ty + i]);
}

// ---- V transpose per (b,h): v[s][h*64+d] -> vt[(b*16+h)*64+d][s] ----------
__global__ __launch_bounds__(256) void vtransp(const u16* __restrict__ v,
                                               u16* __restrict__ vt) {
  __shared__ u16 t[32][34];
  int s0 = blockIdx.x * 32, d0 = blockIdx.y * 32;
  int bh = blockIdx.z; int b = bh >> 4, h = bh & 15;
  int tx = threadIdx.x & 31, ty = threadIdx.x >> 5;
#pragma unroll
  for (int i = 0; i < 32; i += 8)
    t[ty + i][tx] = v[(size_t)(b * 2048 + s0 + ty + i) * 1024 + h * 64 + d0 + tx];
  __syncthreads();
#pragma unroll
  for (int i = 0; i < 32; i += 8)
    vt[((size_t)(b * 16 + h) * 64 + d0 + ty + i) * 2048 + s0 + tx] = t[tx][ty + i];
}

// ---- LayerNorm (1024 cols, no affine) f32 -> bf16 -------------------------
__global__ __launch_bounds__(256) void ln_kernel(const float* __restrict__ x,
                                                 u16* __restrict__ out) {
  int row = blockIdx.x, tid = threadIdx.x;
  const float4* xr = (const float4*)(x + (size_t)row * 1024);
  float4 f = xr[tid];
  float s = f.x + f.y + f.z + f.w;
  float s2 = f.x * f.x + f.y * f.y + f.z * f.z + f.w * f.w;
#pragma unroll
  for (int o = 1; o < 64; o <<= 1) { s += __shfl_xor(s, o); s2 += __shfl_xor(s2, o); }
  __shared__ float red[2][4];
  int wid = tid >> 6;
  if ((tid & 63) == 0) { red[0][wid] = s; red[1][wid] = s2; }
  __syncthreads();
  float tot  = red[0][0] + red[0][1] + red[0][2] + red[0][3];
  float tot2 = red[1][0] + red[1][1] + red[1][2] + red[1][3];
  float mu = tot * (1.0f / 1024.0f);
  float var = tot2 * (1.0f / 1024.0f) - mu * mu;
  float rstd = rsqrtf(var + 1e-5f);
  s16x4 o4;
  o4[0] = (short)f2bf((f.x - mu) * rstd);
  o4[1] = (short)f2bf((f.y - mu) * rstd);
  o4[2] = (short)f2bf((f.z - mu) * rstd);
  o4[3] = (short)f2bf((f.w - mu) * rstd);
  *(s16x4*)(out + (size_t)row * 1024 + tid * 4) = o4;
}

// ---- GEMM: C[M,N] = A[M,K](bf16) * Bt[N,K]^T(bf16), fused epilogues -------
// m97 structure + operand-swap: acc holds C^T fragments (mfma(bfv, af, acc)),
// so per lane the reg quad j=0..3 spans 4 CONSECUTIVE C columns -> vector
// epilogue (ushort4 / float4). Fragment reads & staging identical to verified.
// MODE 0: qkv split -> o0/o1/o2 bf16 (q pre-scaled by 0.125*log2e for attn)
// MODE 1: outF = resid + C (f32)
// MODE 2: o0 = gelu(C + bias) bf16      MODE 3: outF = resid + bias + C (f32)
template <int MODE, int BM>
__global__ __launch_bounds__(256) void gemm_bt(
    const u16* __restrict__ A, const u16* __restrict__ Bt, int N, int K,
    const float* __restrict__ resid, const float* __restrict__ bias,
    float* __restrict__ outF, u16* __restrict__ o0, u16* __restrict__ o1,
    u16* __restrict__ o2) {
  constexpr int MR = BM / 32;                   // acc m-tiles per wave
  __shared__ __align__(16) u16 lA[BM * 32];     // linear: required by global_load_lds
  __shared__ __align__(16) u16 lB[128 * 32];
  int tid = threadIdx.x;
  int lane = tid & 63, wid = tid >> 6;
  int lr = lane & 15, lg = lane >> 4;
  int rowBase = blockIdx.y * BM, colBase = blockIdx.x * 128;
  int wr = (wid >> 1) * (MR * 16), wc = (wid & 1) * 64;

  int srow = wid * 16 + (lane >> 2);
  int scol = (lane & 3) * 8;
  const u16* gA = A + (size_t)(rowBase + srow) * K + scol;
  const u16* gB = Bt + (size_t)(colBase + srow) * K + scol;
  u16* lAb = &lA[wid * 16 * 32];                // wave-uniform base
  u16* lBb = &lB[wid * 16 * 32];

  f32x4 acc[MR][4];
  f32x4 zero = {0.f, 0.f, 0.f, 0.f};
#pragma unroll
  for (int m = 0; m < MR; m++)
#pragma unroll
    for (int n = 0; n < 4; n++) acc[m][n] = zero;

  for (int k0 = 0; k0 < K; k0 += 32) {
    __syncthreads();                            // prior iter's frag reads done
#pragma unroll
    for (int c = 0; c < BM / 64; c++)
      gl16(gA + (size_t)c * 64 * K + k0, lAb + c * 64 * 32);
#pragma unroll
    for (int c = 0; c < 2; c++)
      gl16(gB + (size_t)c * 64 * K + k0, lBb + c * 64 * 32);
    __syncthreads();                            // compiler drains vmcnt here
    bf16x8 af[MR], bfv[4];
#pragma unroll
    for (int m = 0; m < MR; m++)
      af[m] = *(const bf16x8*)&lA[(wr + m * 16 + lr) * 32 + lg * 8];
#pragma unroll
    for (int n = 0; n < 4; n++)
      bfv[n] = *(const bf16x8*)&lB[(wc + n * 16 + lr) * 32 + lg * 8];
#pragma unroll
    for (int m = 0; m < MR; m++)
#pragma unroll
      for (int n = 0; n < 4; n++)               // C^T: swap operands
        acc[m][n] = __builtin_amdgcn_mfma_f32_16x16x32_bf16(bfv[n], af[m], acc[m][n], 0, 0, 0);
  }

  // epilogue: lane holds C rows (m*16+lr), col quad (n*16 + lg*4 + j)
#pragma unroll
  for (int m = 0; m < MR; m++) {
    int grow = rowBase + wr + m * 16 + lr;
#pragma unroll
    for (int n = 0; n < 4; n++) {
      int gcol = colBase + wc + n * 16 + lg * 4;
      f32x4 v4 = acc[m][n];
      if constexpr (MODE == 0) {
        bool isq = gcol < 1024;
        u16* dst = isq ? o0 : ((gcol < 2048) ? o1 : o2);
        s16x4 o4;
#pragma unroll
        for (int j = 0; j < 4; j++)
          o4[j] = (short)f2bf(isq ? v4[j] * 0.18033688011112042f : v4[j]);
        *(s16x4*)&dst[(size_t)grow * 1024 + (gcol & 1023)] = o4;
      } else if constexpr (MODE == 1) {
        size_t idx = (size_t)grow * N + gcol;
        float4 r = *(const float4*)&resid[idx];
        float4 ov = {r.x + v4[0], r.y + v4[1], r.z + v4[2], r.w + v4[3]};
        *(float4*)&outF[idx] = ov;
      } else if constexpr (MODE == 2) {
        float4 bq = *(const float4*)&bias[gcol];
        s16x4 o4;
#pragma unroll
        for (int j = 0; j < 4; j++) {
          float g = v4[j] + ((const float*)&bq)[j];
          // exact tanh-GELU: x - x/(1+exp2(2*sqrt(2/pi)*log2e*(x+0.044715x^3)))
          float e = __builtin_amdgcn_exp2f(2.302208198f * (g + 0.044715f * g * g * g));
          o4[j] = (short)f2bf(g - g * __builtin_amdgcn_rcpf(1.0f + e));
        }
        *(s16x4*)&o0[(size_t)grow * N + gcol] = o4;
      } else {
        size_t idx = (size_t)grow * N + gcol;
        float4 r = *(const float4*)&resid[idx];
        float4 bq = *(const float4*)&bias[gcol];
        float4 ov = {r.x + bq.x + v4[0], r.y + bq.y + v4[1],
                     r.z + bq.z + v4[2], r.w + bq.w + v4[3]};
        *(float4*)&outF[idx] = ov;
      }
    }
  }
}

// ---- Flash attention: block = (b, h, 128 q-rows); 4 waves x 32 rows -------
// Fully swapped (T12): S^T = mfma(K,Q) so q-row = lane&15; O^T = mfma(V^T,P).
// Mx/accL/accO all live in the q=lane&15 domain: rowmax = 15 fmax + 2 shfl.
// P roundtrip: 8 x ds_write_b64 + 4 x ds_read_b128, swizzled. Exp2-domain
// scores (Q pre-scaled), ones-MFMA row-sum, defer-max, T14 prefetch.
__global__ __launch_bounds__(256) void attn_kernel(const u16* __restrict__ q,
                                                   const u16* __restrict__ k,
                                                   const u16* __restrict__ vt,
                                                   u16* __restrict__ o) {
  __shared__ __align__(16) u16 lK[64 * 64];       // [kv][d], swizzled
  __shared__ __align__(16) u16 lV[64 * 64];       // [d][kv], swizzled
  __shared__ __align__(16) u16 lP[4 * 2 * 16 * 64]; // per-wave P[m][q16][kv64], swz
  const int S = 2048, E = 1024;
  int qt = blockIdx.x, h = blockIdx.y, b = blockIdx.z;
  int tid = threadIdx.x, wid = tid >> 6, lane = tid & 63;
  int lr = lane & 15, lg = lane >> 4;
  u16* lPw = &lP[wid * 2048];

  const u16* qp = q + ((size_t)b * S + qt * 128 + wid * 32) * E + h * 64;
  const u16* kp = k + (size_t)b * S * E + h * 64;
  const u16* vp = vt + ((size_t)(b * 16 + h) * 64) * S;

  bf16x8 aQ[2][2];                              // Q hoisted: rows m*16+lr
#pragma unroll
  for (int m = 0; m < 2; m++)
#pragma unroll
    for (int kk = 0; kk < 2; kk++)
      aQ[m][kk] = *(const bf16x8*)(qp + (size_t)(m * 16 + lr) * E + kk * 32 + lg * 8);

  bf16x8 onesv;                                 // all-ones bf16 fragment
#pragma unroll
  for (int i = 0; i < 8; i++) onesv[i] = (short)0x3F80;

  f32x4 accO[2][4], accL[2];
  float Mx[2];
  f32x4 zero = {0.f, 0.f, 0.f, 0.f};
#pragma unroll
  for (int m = 0; m < 2; m++) {
    Mx[m] = -1e30f; accL[m] = zero;
#pragma unroll
    for (int nn = 0; nn < 4; nn++) accO[m][nn] = zero;
  }

  int sr_ = tid >> 3, sc_ = (tid & 7) * 8;      // staging: 32 rows x 64 cols / pass
  const u16* kps0 = kp + (size_t)sr_ * E + sc_;
  const u16* kps1 = kp + (size_t)(sr_ + 32) * E + sc_;
  const u16* vps0 = vp + (size_t)sr_ * S + sc_;
  const u16* vps1 = vp + (size_t)(sr_ + 32) * S + sc_;

  bf16x8 rk0 = *(const bf16x8*)(kps0);          // prologue: tile 0 -> regs
  bf16x8 rk1 = *(const bf16x8*)(kps1);
  bf16x8 rv0 = *(const bf16x8*)(vps0);
  bf16x8 rv1 = *(const bf16x8*)(vps1);

  for (int kv0 = 0; kv0 < S; kv0 += 64) {
    __syncthreads();                            // prior tile fully consumed
    *(bf16x8*)&lK[swzi(sr_, sc_)] = rk0;
    *(bf16x8*)&lK[swzi(32 + sr_, sc_)] = rk1;
    *(bf16x8*)&lV[swzi(sr_, sc_)] = rv0;
    *(bf16x8*)&lV[swzi(32 + sr_, sc_)] = rv1;
    int nx = kv0 + 64;
    if (nx < S) {                               // issue-early: next tile -> regs
      rk0 = *(const bf16x8*)(kps0 + (size_t)nx * E);
      rk1 = *(const bf16x8*)(kps1 + (size_t)nx * E);
      rv0 = *(const bf16x8*)(vps0 + nx);
      rv1 = *(const bf16x8*)(vps1 + nx);
    }
    __syncthreads();                            // lK/lV visible; loads in flight

    // S^T[kv][q] = mfma(K, Q): lane holds q = m*16+lr, kv = n*16 + lg*4 + j
    f32x4 sc4[2][4];
#pragma unroll
    for (int m = 0; m < 2; m++)
#pragma unroll
      for (int n = 0; n < 4; n++) sc4[m][n] = zero;
#pragma unroll
    for (int n = 0; n < 4; n++) {
      bf16x8 bk0 = *(const bf16x8*)&lK[swzi(n * 16 + lr, lg * 8)];
      bf16x8 bk1 = *(const bf16x8*)&lK[swzi(n * 16 + lr, 32 + lg * 8)];
#pragma unroll
      for (int m = 0; m < 2; m++) {
        sc4[m][n] = __builtin_amdgcn_mfma_f32_16x16x32_bf16(bk0, aQ[m][0], sc4[m][n], 0, 0, 0);
        sc4[m][n] = __builtin_amdgcn_mfma_f32_16x16x32_bf16(bk1, aQ[m][1], sc4[m][n], 0, 0, 0);
      }
    }

    // per-q-row max: 15 fmax + 2 shfl (across the lg groups)
    float mxr[2];
#pragma unroll
    for (int m = 0; m < 2; m++) {
      float a0 = fmaxf(fmaxf(sc4[m][0][0], sc4[m][0][1]), fmaxf(sc4[m][0][2], sc4[m][0][3]));
      float a1 = fmaxf(fmaxf(sc4[m][1][0], sc4[m][1][1]), fmaxf(sc4[m][1][2], sc4[m][1][3]));
      float a2 = fmaxf(fmaxf(sc4[m][2][0], sc4[m][2][1]), fmaxf(sc4[m][2][2], sc4[m][2][3]));
      float a3 = fmaxf(fmaxf(sc4[m][3][0], sc4[m][3][1]), fmaxf(sc4[m][3][2], sc4[m][3][3]));
      float mx = fmaxf(fmaxf(a0, a1), fmaxf(a2, a3));
      mx = fmaxf(mx, __shfl_xor(mx, 16));
      mx = fmaxf(mx, __shfl_xor(mx, 32));
      mxr[m] = mx;
    }
    // defer-max (T13, log2 domain, THR=8)
    bool need = (mxr[0] > Mx[0] + 8.f) || (mxr[1] > Mx[1] + 8.f);
    if (__any(need)) {
#pragma unroll
      for (int m = 0; m < 2; m++) {
        float nm = fmaxf(Mx[m], mxr[m]);
        float s = __builtin_amdgcn_exp2f(Mx[m] - nm);
        Mx[m] = nm;
        accL[m] *= s;
#pragma unroll
        for (int nn = 0; nn < 4; nn++) accO[m][nn] *= s;
      }
    }
    // P = exp2(S^T - Mx) -> quad-contiguous ds_write_b64 (row q=lr, cols kv)
#pragma unroll
    for (int m = 0; m < 2; m++)
#pragma unroll
      for (int n = 0; n < 4; n++) {
        s16x4 pq;
#pragma unroll
        for (int j = 0; j < 4; j++)
          pq[j] = (short)f2bf_tr(__builtin_amdgcn_exp2f(sc4[m][n][j] - Mx[m]));
        *(s16x4*)&lPw[m * 1024 + swzi(lr, n * 16 + lg * 4)] = pq;
      }

    // O^T += mfma(V^T, P); L += mfma(ones, P)  (per-wave lP: in-wave ordering)
#pragma unroll
    for (int kk = 0; kk < 2; kk++) {
      bf16x8 ap[2];
#pragma unroll
      for (int m = 0; m < 2; m++)
        ap[m] = *(const bf16x8*)&lPw[m * 1024 + swzi(lr, kk * 32 + lg * 8)];
#pragma unroll
      for (int m = 0; m < 2; m++)
        accL[m] = __builtin_amdgcn_mfma_f32_16x16x32_bf16(onesv, ap[m], accL[m], 0, 0, 0);
#pragma unroll
      for (int nn = 0; nn < 4; nn++) {
        bf16x8 bv = *(const bf16x8*)&lV[swzi(nn * 16 + lr, kk * 32 + lg * 8)];
#pragma unroll
        for (int m = 0; m < 2; m++)
          accO[m][nn] = __builtin_amdgcn_mfma_f32_16x16x32_bf16(bv, ap[m], accO[m][nn], 0, 0, 0);
      }
    }
  }

  // epilogue: O^T frags -> lane owns q-row (m*16+lr), d quad (nn*16+lg*4+j)
#pragma unroll
  for (int m = 0; m < 2; m++) {
    float inv = __builtin_amdgcn_rcpf(accL[m][0]);
    int srow = qt * 128 + wid * 32 + m * 16 + lr;
#pragma unroll
    for (int nn = 0; nn < 4; nn++) {
      s16x4 o4;
#pragma unroll
      for (int j = 0; j < 4; j++) o4[j] = (short)f2bf(accO[m][nn][j] * inv);
      *(s16x4*)&o[((size_t)b * S + srow) * E + h * 64 + nn * 16 + lg * 4] = o4;
    }
  }
}

// ---------------------------------------------------------------------------
extern "C" void kernel_launch(void* const* d_in, const int* in_sizes, int n_in,
                              void* d_out, int out_size, void* d_ws, size_t ws_size,
                              hipStream_t stream) {
  (void)in_sizes; (void)n_in; (void)out_size; (void)ws_size;
  const float* x     = (const float*)d_in[0];
  const float* w_qkv = (const float*)d_in[1];
  const float* w_fc  = (const float*)d_in[2];
  const float* w1    = (const float*)d_in[3];
  const float* b1    = (const float*)d_in[4];
  const float* w2    = (const float*)d_in[5];
  const float* b2    = (const float*)d_in[6];
  float* out = (float*)d_out;
  char* ws = (char*)d_ws;

  // workspace layout (80 MB total)
  u16* wqkvT = (u16*)(ws);                  // [3072][1024] 6 MB
  u16* wfcT  = (u16*)(ws + 6291456);        // [1024][1024] 2 MB
  u16* w1T   = (u16*)(ws + 8388608);        // [4096][1024] 8 MB
  u16* w2T   = (u16*)(ws + 16777216);       // [1024][4096] 8 MB
  u16* hbuf  = (u16*)(ws + 25165824);       // h1 -> attnout -> h2, 8 MB
  u16* qbuf  = (u16*)(ws + 33554432);       // 8 MB
  u16* kbuf  = (u16*)(ws + 41943040);       // 8 MB
  u16* vbuf  = (u16*)(ws + 50331648);       // 8 MB
  u16* vtbuf = (u16*)(ws + 58720256);       // 8 MB
  float* x2  = (float*)(ws + 67108864);     // 16 MB f32
  u16* act   = qbuf;                        // [4096][4096] 32 MB over q..vt (dead)

  wcastT<<<dim3(96, 32), 256, 0, stream>>>(w_qkv, wqkvT, 1024, 3072);
  wcastT<<<dim3(32, 32), 256, 0, stream>>>(w_fc, wfcT, 1024, 1024);
  wcastT<<<dim3(128, 32), 256, 0, stream>>>(w1, w1T, 1024, 4096);
  wcastT<<<dim3(32, 128), 256, 0, stream>>>(w2, w2T, 4096, 1024);

  ln_kernel<<<4096, 256, 0, stream>>>(x, hbuf);
  gemm_bt<0, 128><<<dim3(24, 32), 256, 0, stream>>>(hbuf, wqkvT, 3072, 1024,
                                                    nullptr, nullptr, nullptr, qbuf, kbuf, vbuf);
  vtransp<<<dim3(64, 2, 32), 256, 0, stream>>>(vbuf, vtbuf);
  attn_kernel<<<dim3(16, 16, 2), 256, 0, stream>>>(qbuf, kbuf, vtbuf, hbuf);
  gemm_bt<1, 64><<<dim3(8, 64), 256, 0, stream>>>(hbuf, wfcT, 1024, 1024,
                                                  x, nullptr, x2, nullptr, nullptr, nullptr);
  ln_kernel<<<4096, 256, 0, stream>>>(x2, hbuf);
  gemm_bt<2, 128><<<dim3(32, 32), 256, 0, stream>>>(hbuf, w1T, 4096, 1024,
                                                    nullptr, b1, nullptr, act, nullptr, nullptr);
  gemm_bt<3, 64><<<dim3(8, 64), 256, 0, stream>>>(act, w2T, 1024, 4096,
                                                  x2, b2, out, nullptr, nullptr, nullptr);
}

// Round 5
// 267.710 us; speedup vs baseline: 1.4291x; 1.0955x over previous
//
#include <hip/hip_runtime.h>

typedef unsigned short u16;
typedef __attribute__((ext_vector_type(8))) short bf16x8;   // 8 x bf16 (4 VGPRs)
typedef __attribute__((ext_vector_type(4))) short s16x4;
typedef __attribute__((ext_vector_type(4))) float f32x4;

#define DEV __device__ __forceinline__

DEV u16 f2bf(float f) {                       // fp32 -> bf16 bits, RNE
  union { float f; unsigned u; } v; v.f = f;
  unsigned r = v.u + 0x7fffu + ((v.u >> 16) & 1u);
  return (u16)(r >> 16);
}
DEV u16 f2bf_tr(float f) {                    // truncating (P only; bias cancels in O/l)
  union { float f; unsigned u; } v; v.f = f;
  return (u16)(v.u >> 16);
}

// XOR bank-swizzle for a 64-col bf16 LDS tile (u16 index units).
DEV int swzi(int row, int col) { return row * 64 + (col ^ ((row & 7) << 3)); }

// async global->LDS, 16B per lane. LDS dest is wave-uniform base; HW adds lane*16.
DEV void gl16(const u16* g, u16* l) {
  __builtin_amdgcn_global_load_lds((const __attribute__((address_space(1))) void*)g,
                                   (__attribute__((address_space(3))) void*)l, 16, 0, 0);
}

// ---- weight cast + transpose: w[K][N] f32 -> wt[N][K] bf16 ----------------
__global__ __launch_bounds__(256) void wcastT(const float* __restrict__ w,
                                              u16* __restrict__ wt, int K, int N) {
  __shared__ float t[32][33];
  int n0 = blockIdx.x * 32, k0 = blockIdx.y * 32;
  int tx = threadIdx.x & 31, ty = threadIdx.x >> 5;
#pragma unroll
  for (int i = 0; i < 32; i += 8)
    t[ty + i][tx] = w[(size_t)(k0 + ty + i) * N + n0 + tx];
  __syncthreads();
#pragma unroll
  for (int i = 0; i < 32; i += 8)
    wt[(size_t)(n0 + ty + i) * K + k0 + tx] = f2bf(t[tx][ty + i]);
}

// ---- V transpose per (b,h): v[s][h*64+d] -> vt[(b*16+h)*64+d][s] ----------
__global__ __launch_bounds__(256) void vtransp(const u16* __restrict__ v,
                                               u16* __restrict__ vt) {
  __shared__ u16 t[32][34];
  int s0 = blockIdx.x * 32, d0 = blockIdx.y * 32;
  int bh = blockIdx.z; int b = bh >> 4, h = bh & 15;
  int tx = threadIdx.x & 31, ty = threadIdx.x >> 5;
#pragma unroll
  for (int i = 0; i < 32; i += 8)
    t[ty + i][tx] = v[(size_t)(b * 2048 + s0 + ty + i) * 1024 + h * 64 + d0 + tx];
  __syncthreads();
#pragma unroll
  for (int i = 0; i < 32; i += 8)
    vt[((size_t)(b * 16 + h) * 64 + d0 + ty + i) * 2048 + s0 + tx] = t[tx][ty + i];
}

// ---- LayerNorm (1024 cols, no affine) f32 -> bf16 -------------------------
__global__ __launch_bounds__(256) void ln_kernel(const float* __restrict__ x,
                                                 u16* __restrict__ out) {
  int row = blockIdx.x, tid = threadIdx.x;
  const float4* xr = (const float4*)(x + (size_t)row * 1024);
  float4 f = xr[tid];
  float s = f.x + f.y + f.z + f.w;
  float s2 = f.x * f.x + f.y * f.y + f.z * f.z + f.w * f.w;
#pragma unroll
  for (int o = 1; o < 64; o <<= 1) { s += __shfl_xor(s, o); s2 += __shfl_xor(s2, o); }
  __shared__ float red[2][4];
  int wid = tid >> 6;
  if ((tid & 63) == 0) { red[0][wid] = s; red[1][wid] = s2; }
  __syncthreads();
  float tot  = red[0][0] + red[0][1] + red[0][2] + red[0][3];
  float tot2 = red[1][0] + red[1][1] + red[1][2] + red[1][3];
  float mu = tot * (1.0f / 1024.0f);
  float var = tot2 * (1.0f / 1024.0f) - mu * mu;
  float rstd = rsqrtf(var + 1e-5f);
  s16x4 o4;
  o4[0] = (short)f2bf((f.x - mu) * rstd);
  o4[1] = (short)f2bf((f.y - mu) * rstd);
  o4[2] = (short)f2bf((f.z - mu) * rstd);
  o4[3] = (short)f2bf((f.w - mu) * rstd);
  *(s16x4*)(out + (size_t)row * 1024 + tid * 4) = o4;
}

// ---- GEMM: C[M,N] = A[M,K](bf16) * Bt[N,K]^T(bf16), fused epilogues -------
// m97 fragments + C^T operand-swap epilogue + T1 XCD-chunked block swizzle +
// 2-phase double-buffered K-loop (stage next tile, compute current, ONE
// barrier per step -> global_load_lds latency hides under MFMA/ds_read).
// MODE 0: qkv split -> o0/o1/o2 bf16 (q pre-scaled by 0.125*log2e for attn)
// MODE 1: outF = resid + C (f32)
// MODE 2: o0 = gelu(C + bias) bf16      MODE 3: outF = resid + bias + C (f32)
template <int MODE, int BM>
__global__ __launch_bounds__(256) void gemm_bt(
    const u16* __restrict__ A, const u16* __restrict__ Bt, int N, int K,
    const float* __restrict__ resid, const float* __restrict__ bias,
    float* __restrict__ outF, u16* __restrict__ o0, u16* __restrict__ o1,
    u16* __restrict__ o2) {
  constexpr int MR = BM / 32;                   // acc m-tiles per wave
  constexpr int ASZ = BM * 32, BSZ = 128 * 32;  // u16 elems per buffer
  __shared__ __align__(16) u16 lA[2 * ASZ];     // linear (global_load_lds) x2 buf
  __shared__ __align__(16) u16 lB[2 * BSZ];
  int tid = threadIdx.x;
  int lane = tid & 63, wid = tid >> 6;
  int lr = lane & 15, lg = lane >> 4;

  // T1: XCD-chunked swizzle (nwg % 8 == 0 for all our grids -> bijective)
  int gx = gridDim.x;
  int nwg = gx * gridDim.y;
  int bid = blockIdx.y * gx + blockIdx.x;
  int swz = (bid & 7) * (nwg >> 3) + (bid >> 3);
  int rowBase = (swz / gx) * BM, colBase = (swz % gx) * 128;
  int wr = (wid >> 1) * (MR * 16), wc = (wid & 1) * 64;

  int srow = wid * 16 + (lane >> 2);
  int scol = (lane & 3) * 8;
  const u16* gA = A + (size_t)(rowBase + srow) * K + scol;
  const u16* gB = Bt + (size_t)(colBase + srow) * K + scol;
  u16* lAb = &lA[wid * 16 * 32];                // wave-uniform base (buf 0)
  u16* lBb = &lB[wid * 16 * 32];

  f32x4 acc[MR][4];
  f32x4 zero = {0.f, 0.f, 0.f, 0.f};
#pragma unroll
  for (int m = 0; m < MR; m++)
#pragma unroll
    for (int n = 0; n < 4; n++) acc[m][n] = zero;

  // prologue: stage tile 0 into buffer 0
#pragma unroll
  for (int c = 0; c < BM / 64; c++)
    gl16(gA + (size_t)c * 64 * K, lAb + c * 64 * 32);
#pragma unroll
  for (int c = 0; c < 2; c++)
    gl16(gB + (size_t)c * 64 * K, lBb + c * 64 * 32);
  __syncthreads();                              // drains vmcnt(0)

  int nt = K >> 5;
  for (int t = 0; t < nt; t++) {
    int cur = t & 1;
    if (t + 1 < nt) {                           // issue next-tile loads FIRST
      int k1 = (t + 1) << 5;
      int nb = cur ^ 1;
#pragma unroll
      for (int c = 0; c < BM / 64; c++)
        gl16(gA + (size_t)c * 64 * K + k1, lAb + nb * ASZ + c * 64 * 32);
#pragma unroll
      for (int c = 0; c < 2; c++)
        gl16(gB + (size_t)c * 64 * K + k1, lBb + nb * BSZ + c * 64 * 32);
    }
    const u16* cA = &lA[cur * ASZ];
    const u16* cB = &lB[cur * BSZ];
    bf16x8 af[MR], bfv[4];
#pragma unroll
    for (int m = 0; m < MR; m++)
      af[m] = *(const bf16x8*)&cA[(wr + m * 16 + lr) * 32 + lg * 8];
#pragma unroll
    for (int n = 0; n < 4; n++)
      bfv[n] = *(const bf16x8*)&cB[(wc + n * 16 + lr) * 32 + lg * 8];
#pragma unroll
    for (int m = 0; m < MR; m++)
#pragma unroll
      for (int n = 0; n < 4; n++)               // C^T: swap operands
        acc[m][n] = __builtin_amdgcn_mfma_f32_16x16x32_bf16(bfv[n], af[m], acc[m][n], 0, 0, 0);
    __syncthreads();                            // next-tile staged + reads done
  }

  // epilogue: lane holds C rows (m*16+lr), col quad (n*16 + lg*4 + j)
#pragma unroll
  for (int m = 0; m < MR; m++) {
    int grow = rowBase + wr + m * 16 + lr;
#pragma unroll
    for (int n = 0; n < 4; n++) {
      int gcol = colBase + wc + n * 16 + lg * 4;
      f32x4 v4 = acc[m][n];
      if constexpr (MODE == 0) {
        bool isq = gcol < 1024;
        u16* dst = isq ? o0 : ((gcol < 2048) ? o1 : o2);
        s16x4 o4;
#pragma unroll
        for (int j = 0; j < 4; j++)
          o4[j] = (short)f2bf(isq ? v4[j] * 0.18033688011112042f : v4[j]);
        *(s16x4*)&dst[(size_t)grow * 1024 + (gcol & 1023)] = o4;
      } else if constexpr (MODE == 1) {
        size_t idx = (size_t)grow * N + gcol;
        float4 r = *(const float4*)&resid[idx];
        float4 ov = {r.x + v4[0], r.y + v4[1], r.z + v4[2], r.w + v4[3]};
        *(float4*)&outF[idx] = ov;
      } else if constexpr (MODE == 2) {
        float4 bq = *(const float4*)&bias[gcol];
        s16x4 o4;
#pragma unroll
        for (int j = 0; j < 4; j++) {
          float g = v4[j] + ((const float*)&bq)[j];
          // exact tanh-GELU: x - x/(1+exp2(2*sqrt(2/pi)*log2e*(x+0.044715x^3)))
          float e = __builtin_amdgcn_exp2f(2.302208198f * (g + 0.044715f * g * g * g));
          o4[j] = (short)f2bf(g - g * __builtin_amdgcn_rcpf(1.0f + e));
        }
        *(s16x4*)&o0[(size_t)grow * N + gcol] = o4;
      } else {
        size_t idx = (size_t)grow * N + gcol;
        float4 r = *(const float4*)&resid[idx];
        float4 bq = *(const float4*)&bias[gcol];
        float4 ov = {r.x + bq.x + v4[0], r.y + bq.y + v4[1],
                     r.z + bq.z + v4[2], r.w + bq.w + v4[3]};
        *(float4*)&outF[idx] = ov;
      }
    }
  }
}

// ---- Flash attention: block = (b, h, 128 q-rows); 4 waves x 32 rows -------
// Fully swapped (T12): S^T = mfma(K,Q) so q-row = lane&15; O^T = mfma(V^T,P).
__global__ __launch_bounds__(256) void attn_kernel(const u16* __restrict__ q,
                                                   const u16* __restrict__ k,
                                                   const u16* __restrict__ vt,
                                                   u16* __restrict__ o) {
  __shared__ __align__(16) u16 lK[64 * 64];       // [kv][d], swizzled
  __shared__ __align__(16) u16 lV[64 * 64];       // [d][kv], swizzled
  __shared__ __align__(16) u16 lP[4 * 2 * 16 * 64]; // per-wave P[m][q16][kv64], swz
  const int S = 2048, E = 1024;
  int qt = blockIdx.x, h = blockIdx.y, b = blockIdx.z;
  int tid = threadIdx.x, wid = tid >> 6, lane = tid & 63;
  int lr = lane & 15, lg = lane >> 4;
  u16* lPw = &lP[wid * 2048];

  const u16* qp = q + ((size_t)b * S + qt * 128 + wid * 32) * E + h * 64;
  const u16* kp = k + (size_t)b * S * E + h * 64;
  const u16* vp = vt + ((size_t)(b * 16 + h) * 64) * S;

  bf16x8 aQ[2][2];                              // Q hoisted: rows m*16+lr
#pragma unroll
  for (int m = 0; m < 2; m++)
#pragma unroll
    for (int kk = 0; kk < 2; kk++)
      aQ[m][kk] = *(const bf16x8*)(qp + (size_t)(m * 16 + lr) * E + kk * 32 + lg * 8);

  bf16x8 onesv;                                 // all-ones bf16 fragment
#pragma unroll
  for (int i = 0; i < 8; i++) onesv[i] = (short)0x3F80;

  f32x4 accO[2][4], accL[2];
  float Mx[2];
  f32x4 zero = {0.f, 0.f, 0.f, 0.f};
#pragma unroll
  for (int m = 0; m < 2; m++) {
    Mx[m] = -1e30f; accL[m] = zero;
#pragma unroll
    for (int nn = 0; nn < 4; nn++) accO[m][nn] = zero;
  }

  int sr_ = tid >> 3, sc_ = (tid & 7) * 8;      // staging: 32 rows x 64 cols / pass
  const u16* kps0 = kp + (size_t)sr_ * E + sc_;
  const u16* kps1 = kp + (size_t)(sr_ + 32) * E + sc_;
  const u16* vps0 = vp + (size_t)sr_ * S + sc_;
  const u16* vps1 = vp + (size_t)(sr_ + 32) * S + sc_;

  bf16x8 rk0 = *(const bf16x8*)(kps0);          // prologue: tile 0 -> regs
  bf16x8 rk1 = *(const bf16x8*)(kps1);
  bf16x8 rv0 = *(const bf16x8*)(vps0);
  bf16x8 rv1 = *(const bf16x8*)(vps1);

  for (int kv0 = 0; kv0 < S; kv0 += 64) {
    __syncthreads();                            // prior tile fully consumed
    *(bf16x8*)&lK[swzi(sr_, sc_)] = rk0;
    *(bf16x8*)&lK[swzi(32 + sr_, sc_)] = rk1;
    *(bf16x8*)&lV[swzi(sr_, sc_)] = rv0;
    *(bf16x8*)&lV[swzi(32 + sr_, sc_)] = rv1;
    int nx = kv0 + 64;
    if (nx < S) {                               // issue-early: next tile -> regs
      rk0 = *(const bf16x8*)(kps0 + (size_t)nx * E);
      rk1 = *(const bf16x8*)(kps1 + (size_t)nx * E);
      rv0 = *(const bf16x8*)(vps0 + nx);
      rv1 = *(const bf16x8*)(vps1 + nx);
    }
    __syncthreads();                            // lK/lV visible; loads in flight

    // S^T[kv][q] = mfma(K, Q): lane holds q = m*16+lr, kv = n*16 + lg*4 + j
    f32x4 sc4[2][4];
#pragma unroll
    for (int m = 0; m < 2; m++)
#pragma unroll
      for (int n = 0; n < 4; n++) sc4[m][n] = zero;
#pragma unroll
    for (int n = 0; n < 4; n++) {
      bf16x8 bk0 = *(const bf16x8*)&lK[swzi(n * 16 + lr, lg * 8)];
      bf16x8 bk1 = *(const bf16x8*)&lK[swzi(n * 16 + lr, 32 + lg * 8)];
#pragma unroll
      for (int m = 0; m < 2; m++) {
        sc4[m][n] = __builtin_amdgcn_mfma_f32_16x16x32_bf16(bk0, aQ[m][0], sc4[m][n], 0, 0, 0);
        sc4[m][n] = __builtin_amdgcn_mfma_f32_16x16x32_bf16(bk1, aQ[m][1], sc4[m][n], 0, 0, 0);
      }
    }

    // per-q-row max: 15 fmax + 2 shfl (across the lg groups)
    float mxr[2];
#pragma unroll
    for (int m = 0; m < 2; m++) {
      float a0 = fmaxf(fmaxf(sc4[m][0][0], sc4[m][0][1]), fmaxf(sc4[m][0][2], sc4[m][0][3]));
      float a1 = fmaxf(fmaxf(sc4[m][1][0], sc4[m][1][1]), fmaxf(sc4[m][1][2], sc4[m][1][3]));
      float a2 = fmaxf(fmaxf(sc4[m][2][0], sc4[m][2][1]), fmaxf(sc4[m][2][2], sc4[m][2][3]));
      float a3 = fmaxf(fmaxf(sc4[m][3][0], sc4[m][3][1]), fmaxf(sc4[m][3][2], sc4[m][3][3]));
      float mx = fmaxf(fmaxf(a0, a1), fmaxf(a2, a3));
      mx = fmaxf(mx, __shfl_xor(mx, 16));
      mx = fmaxf(mx, __shfl_xor(mx, 32));
      mxr[m] = mx;
    }
    // defer-max (T13, log2 domain, THR=8)
    bool need = (mxr[0] > Mx[0] + 8.f) || (mxr[1] > Mx[1] + 8.f);
    if (__any(need)) {
#pragma unroll
      for (int m = 0; m < 2; m++) {
        float nm = fmaxf(Mx[m], mxr[m]);
        float s = __builtin_amdgcn_exp2f(Mx[m] - nm);
        Mx[m] = nm;
        accL[m] *= s;
#pragma unroll
        for (int nn = 0; nn < 4; nn++) accO[m][nn] *= s;
      }
    }
    // P = exp2(S^T - Mx) -> quad-contiguous ds_write_b64 (row q=lr, cols kv)
#pragma unroll
    for (int m = 0; m < 2; m++)
#pragma unroll
      for (int n = 0; n < 4; n++) {
        s16x4 pq;
#pragma unroll
        for (int j = 0; j < 4; j++)
          pq[j] = (short)f2bf_tr(__builtin_amdgcn_exp2f(sc4[m][n][j] - Mx[m]));
        *(s16x4*)&lPw[m * 1024 + swzi(lr, n * 16 + lg * 4)] = pq;
      }

    // O^T += mfma(V^T, P); L += mfma(ones, P)  (per-wave lP: in-wave ordering)
#pragma unroll
    for (int kk = 0; kk < 2; kk++) {
      bf16x8 ap[2];
#pragma unroll
      for (int m = 0; m < 2; m++)
        ap[m] = *(const bf16x8*)&lPw[m * 1024 + swzi(lr, kk * 32 + lg * 8)];
#pragma unroll
      for (int m = 0; m < 2; m++)
        accL[m] = __builtin_amdgcn_mfma_f32_16x16x32_bf16(onesv, ap[m], accL[m], 0, 0, 0);
#pragma unroll
      for (int nn = 0; nn < 4; nn++) {
        bf16x8 bv = *(const bf16x8*)&lV[swzi(nn * 16 + lr, kk * 32 + lg * 8)];
#pragma unroll
        for (int m = 0; m < 2; m++)
          accO[m][nn] = __builtin_amdgcn_mfma_f32_16x16x32_bf16(bv, ap[m], accO[m][nn], 0, 0, 0);
      }
    }
  }

  // epilogue: O^T frags -> lane owns q-row (m*16+lr), d quad (nn*16+lg*4+j)
#pragma unroll
  for (int m = 0; m < 2; m++) {
    float inv = __builtin_amdgcn_rcpf(accL[m][0]);
    int srow = qt * 128 + wid * 32 + m * 16 + lr;
#pragma unroll
    for (int nn = 0; nn < 4; nn++) {
      s16x4 o4;
#pragma unroll
      for (int j = 0; j < 4; j++) o4[j] = (short)f2bf(accO[m][nn][j] * inv);
      *(s16x4*)&o[((size_t)b * S + srow) * E + h * 64 + nn * 16 + lg * 4] = o4;
    }
  }
}

// ---------------------------------------------------------------------------
extern "C" void kernel_launch(void* const* d_in, const int* in_sizes, int n_in,
                              void* d_out, int out_size, void* d_ws, size_t ws_size,
                              hipStream_t stream) {
  (void)in_sizes; (void)n_in; (void)out_size; (void)ws_size;
  const float* x     = (const float*)d_in[0];
  const float* w_qkv = (const float*)d_in[1];
  const float* w_fc  = (const float*)d_in[2];
  const float* w1    = (const float*)d_in[3];
  const float* b1    = (const float*)d_in[4];
  const float* w2    = (const float*)d_in[5];
  const float* b2    = (const float*)d_in[6];
  float* out = (float*)d_out;
  char* ws = (char*)d_ws;

  // workspace layout (80 MB total)
  u16* wqkvT = (u16*)(ws);                  // [3072][1024] 6 MB
  u16* wfcT  = (u16*)(ws + 6291456);        // [1024][1024] 2 MB
  u16* w1T   = (u16*)(ws + 8388608);        // [4096][1024] 8 MB
  u16* w2T   = (u16*)(ws + 16777216);       // [1024][4096] 8 MB
  u16* hbuf  = (u16*)(ws + 25165824);       // h1 -> attnout -> h2, 8 MB
  u16* qbuf  = (u16*)(ws + 33554432);       // 8 MB
  u16* kbuf  = (u16*)(ws + 41943040);       // 8 MB
  u16* vbuf  = (u16*)(ws + 50331648);       // 8 MB
  u16* vtbuf = (u16*)(ws + 58720256);       // 8 MB
  float* x2  = (float*)(ws + 67108864);     // 16 MB f32
  u16* act   = qbuf;                        // [4096][4096] 32 MB over q..vt (dead)

  wcastT<<<dim3(96, 32), 256, 0, stream>>>(w_qkv, wqkvT, 1024, 3072);
  wcastT<<<dim3(32, 32), 256, 0, stream>>>(w_fc, wfcT, 1024, 1024);
  wcastT<<<dim3(128, 32), 256, 0, stream>>>(w1, w1T, 1024, 4096);
  wcastT<<<dim3(32, 128), 256, 0, stream>>>(w2, w2T, 4096, 1024);

  ln_kernel<<<4096, 256, 0, stream>>>(x, hbuf);
  gemm_bt<0, 128><<<dim3(24, 32), 256, 0, stream>>>(hbuf, wqkvT, 3072, 1024,
                                                    nullptr, nullptr, nullptr, qbuf, kbuf, vbuf);
  vtransp<<<dim3(64, 2, 32), 256, 0, stream>>>(vbuf, vtbuf);
  attn_kernel<<<dim3(16, 16, 2), 256, 0, stream>>>(qbuf, kbuf, vtbuf, hbuf);
  gemm_bt<1, 64><<<dim3(8, 64), 256, 0, stream>>>(hbuf, wfcT, 1024, 1024,
                                                  x, nullptr, x2, nullptr, nullptr, nullptr);
  ln_kernel<<<4096, 256, 0, stream>>>(x2, hbuf);
  gemm_bt<2, 128><<<dim3(32, 32), 256, 0, stream>>>(hbuf, w1T, 4096, 1024,
                                                    nullptr, b1, nullptr, act, nullptr, nullptr);
  gemm_bt<3, 64><<<dim3(8, 64), 256, 0, stream>>>(act, w2T, 1024, 4096,
                                                  x2, b2, out, nullptr, nullptr, nullptr);
}